// Round 1
// baseline (559.389 us; speedup 1.0000x reference)
//
#include <hip/hip_runtime.h>
#include <hip/hip_bf16.h>

// Problem constants (QuantizedLinear): T=8192 rows, N=K=4096, M=4096, RANK=64,
// CODESZ=8, CB_SIZE=256. Workspace requirement: 8192*4096*2 + 4096*4096*2 =
// 100,663,296 bytes (x_bf16 + W_eff bf16).

typedef __attribute__((ext_vector_type(8))) short short8;
typedef __attribute__((ext_vector_type(4))) float f32x4;

#define T_ROWS 8192
#define NDIM   4096
#define MDIM   4096

// ---------------------------------------------------------------------------
// global -> LDS async copy, 16B per lane. LDS dest must be wave-uniform base;
// lane lands at base + lane*16. AS plumbing via inttoptr (flat->LDS addr is a
// 32-bit truncate on gfx9+).
__device__ __forceinline__ void gld_lds16(const void* g, void* lds_uniform) {
    __builtin_amdgcn_global_load_lds(
        (const __attribute__((address_space(1))) unsigned int*)(unsigned long long)(uintptr_t)g,
        (__attribute__((address_space(3))) unsigned int*)(unsigned int)(uintptr_t)lds_uniform,
        16, 0, 0);
}

__device__ __forceinline__ void bfly(float& a, float& b) {
    float s = a + b, d = a - b; a = s; b = d;
}
__device__ __forceinline__ void bfly4(float4& a, float4& b) {
    bfly(a.x, b.x); bfly(a.y, b.y); bfly(a.z, b.z); bfly(a.w, b.w);
}

// ---------------------------------------------------------------------------
// k1: x = fwht(input * SU) / 64, output bf16.
// One block per row. Thread t owns elements 4*(t+256s)+j  (s=0..3, j=0..3):
// index bits {0,1} within float4, bits {10,11} across s -> 4 register stages
// (h=1,2,1024,2048). Remaining stages h=4..512 in LDS. Stage order is free
// (each stage touches a distinct bit).
__global__ __launch_bounds__(256) void fwht_in_kernel(
        const float* __restrict__ in, const float* __restrict__ SU,
        __hip_bfloat16* __restrict__ xout) {
    __shared__ float sh[4096];
    const int t = threadIdx.x;
    const size_t r = blockIdx.x;
    const float4* src = (const float4*)(in + (r << 12));
    const float4* su4 = (const float4*)SU;

    float4 v[4];
#pragma unroll
    for (int s = 0; s < 4; ++s) {
        float4 a = src[t + (s << 8)];
        float4 u = su4[t + (s << 8)];
        a.x *= u.x; a.y *= u.y; a.z *= u.z; a.w *= u.w;
        v[s] = a;
    }
    // h=1, h=2 (bits 0,1)
#pragma unroll
    for (int s = 0; s < 4; ++s) {
        bfly(v[s].x, v[s].y); bfly(v[s].z, v[s].w);   // h=1
        bfly(v[s].x, v[s].z); bfly(v[s].y, v[s].w);   // h=2
    }
    // h=1024 (bit 10 = s bit 0), h=2048 (bit 11 = s bit 1)
    bfly4(v[0], v[1]); bfly4(v[2], v[3]);
    bfly4(v[0], v[2]); bfly4(v[1], v[3]);

#pragma unroll
    for (int s = 0; s < 4; ++s) ((float4*)sh)[t + (s << 8)] = v[s];

#pragma unroll
    for (int h = 4; h <= 512; h <<= 1) {
        __syncthreads();
#pragma unroll
        for (int s = 0; s < 8; ++s) {
            int p = t + (s << 8);                       // pair id 0..2047
            int i = ((p & ~(h - 1)) << 1) | (p & (h - 1));
            float a = sh[i], b = sh[i + h];
            sh[i] = a + b; sh[i + h] = a - b;
        }
    }
    __syncthreads();

    __hip_bfloat16* dst = xout + (r << 12);
    const float sc = 0.015625f;  // 1/64
#pragma unroll
    for (int s = 0; s < 4; ++s) {
        float4 a = ((const float4*)sh)[t + (s << 8)];
        union { __hip_bfloat16 h[4]; unsigned long long u; } pk;
        pk.h[0] = __float2bfloat16(a.x * sc);
        pk.h[1] = __float2bfloat16(a.y * sc);
        pk.h[2] = __float2bfloat16(a.z * sc);
        pk.h[3] = __float2bfloat16(a.w * sc);
        ((unsigned long long*)dst)[t + (s << 8)] = pk.u;
    }
}

// ---------------------------------------------------------------------------
// k2: W_eff[i][j] = codebook[Qidxs[i][j/8]][j%8]*Wscale + (A@B)[i][j], bf16.
// 64x64 tile per block, rank-64 f32 accumulation, A staged transposed in LDS
// so the inner loop is two ds_read_b128 per k.
__global__ __launch_bounds__(256) void dequant_kernel(
        const int* __restrict__ Qidxs, const float* __restrict__ cb,
        const float* __restrict__ Wscale, const float* __restrict__ A,
        const float* __restrict__ B, __hip_bfloat16* __restrict__ Weff) {
    __shared__ float At[64][68];   // A^T tile: At[k][r]
    __shared__ float Bs[64][68];   // Bs[k][c]
    __shared__ float cbs[2048];    // codebook 256x8
    const int t = threadIdx.x;
    const int i0 = blockIdx.y * 64, j0 = blockIdx.x * 64;

    {   // A tile (rows i0..i0+63, all 64 ranks), store transposed
        const float* ga = A + (size_t)i0 * 64;
        const int r = t >> 2, kb = (t & 3) * 16;
#pragma unroll
        for (int j = 0; j < 16; ++j) At[kb + j][r] = ga[t * 16 + j];
        // B tile: Bs[k][c] = B[k*4096 + j0 + c]
        const int k = t >> 2, c0 = (t & 3) * 16;
        const float* gb = B + (size_t)k * NDIM + j0 + c0;
#pragma unroll
        for (int j = 0; j < 16; ++j) Bs[k][c0 + j] = gb[j];
#pragma unroll
        for (int j = 0; j < 8; ++j) cbs[t * 8 + j] = cb[t * 8 + j];
    }
    __syncthreads();

    const int ty = t >> 4, tx = t & 15;
    float acc[4][4];
#pragma unroll
    for (int a = 0; a < 4; ++a)
#pragma unroll
        for (int b = 0; b < 4; ++b) acc[a][b] = 0.f;

#pragma unroll 8
    for (int k = 0; k < 64; ++k) {
        const float4 av = *(const float4*)&At[k][ty * 4];
        const float4 bv = *(const float4*)&Bs[k][tx * 4];
        const float aa[4] = {av.x, av.y, av.z, av.w};
        const float bb[4] = {bv.x, bv.y, bv.z, bv.w};
#pragma unroll
        for (int ii = 0; ii < 4; ++ii)
#pragma unroll
            for (int jj = 0; jj < 4; ++jj) acc[ii][jj] += aa[ii] * bb[jj];
    }

    const float wsc = Wscale[0];
#pragma unroll
    for (int ii = 0; ii < 4; ++ii) {
        const int i = i0 + ty * 4 + ii;
        const int* qrow = Qidxs + (size_t)i * (NDIM / 8);
        union { __hip_bfloat16 h[4]; unsigned long long u; } pk;
#pragma unroll
        for (int jj = 0; jj < 4; ++jj) {
            const int j = j0 + tx * 4 + jj;
            const int idx = qrow[j >> 3];
            const float val = cbs[idx * 8 + (j & 7)] * wsc + acc[ii][jj];
            pk.h[jj] = __float2bfloat16(val);
        }
        *(unsigned long long*)&Weff[(size_t)i * NDIM + j0 + tx * 4] = pk.u;
    }
}

// ---------------------------------------------------------------------------
// k3: z[t][i] = sum_k x[t][k] * Weff[i][k]  (NT GEMM, both K-contiguous).
// m97 structure: 128x128 tile, BK=32, 4 waves (each a 64x64 quadrant),
// 16x16x32 bf16 MFMA, global_load_lds width-16 staging, 2 barriers/K-step.
__global__ __launch_bounds__(256) void gemm_bt_kernel(
        const __hip_bfloat16* __restrict__ X, const __hip_bfloat16* __restrict__ W,
        float* __restrict__ Z) {
    __shared__ __align__(16) __hip_bfloat16 As[128 * 32];
    __shared__ __align__(16) __hip_bfloat16 Bs[128 * 32];

    // XCD-bijective swizzle: 2048 blocks, 2048 % 8 == 0
    const int b = blockIdx.x;
    const int swz = (b & 7) * 256 + (b >> 3);
    const int bm = swz >> 5;           // 64 row tiles (T/128)
    const int bn = swz & 31;           // 32 col tiles (M/128)
    const size_t row0 = (size_t)bm * 128, col0 = (size_t)bn * 128;

    const int t = threadIdx.x, w = t >> 6, lane = t & 63;
    const int wm = w >> 1, wn = w & 1;           // 2x2 wave grid
    const int lr = lane & 15, kg = (lane >> 4) << 3;

    f32x4 acc[4][4];
#pragma unroll
    for (int m = 0; m < 4; ++m)
#pragma unroll
        for (int n = 0; n < 4; ++n) acc[m][n] = 0.f;

    // staging geometry: per issue q, this lane covers tile elements
    // e = q*2048 + w*512 + lane*8 .. +8  (row = e>>5, col = e&31)
    const int e0 = (w << 9) + lane * 8;
    const int r0a = e0 >> 5, c0a = e0 & 31;      // q=0
    const int e1 = 2048 + e0;
    const int r1a = e1 >> 5, c1a = e1 & 31;      // q=1
    __hip_bfloat16* ldsA0 = &As[(w << 9)];
    __hip_bfloat16* ldsA1 = &As[2048 + (w << 9)];
    __hip_bfloat16* ldsB0 = &Bs[(w << 9)];
    __hip_bfloat16* ldsB1 = &Bs[2048 + (w << 9)];

    for (int kt = 0; kt < NDIM / 32; ++kt) {
        const int k0 = kt * 32;
        __syncthreads();   // previous iteration's reads done
        gld_lds16(X + (row0 + r0a) * NDIM + k0 + c0a, ldsA0);
        gld_lds16(X + (row0 + r1a) * NDIM + k0 + c1a, ldsA1);
        gld_lds16(W + (col0 + r0a) * NDIM + k0 + c0a, ldsB0);
        gld_lds16(W + (col0 + r1a) * NDIM + k0 + c1a, ldsB1);
        __syncthreads();   // drains vmcnt before barrier (compiler-inserted)

        short8 af[4], bf[4];
#pragma unroll
        for (int m = 0; m < 4; ++m)
            af[m] = *(const short8*)&As[((wm << 6) + (m << 4) + lr) * 32 + kg];
#pragma unroll
        for (int n = 0; n < 4; ++n)
            bf[n] = *(const short8*)&Bs[((wn << 6) + (n << 4) + lr) * 32 + kg];
#pragma unroll
        for (int m = 0; m < 4; ++m)
#pragma unroll
            for (int n = 0; n < 4; ++n)
                acc[m][n] = __builtin_amdgcn_mfma_f32_16x16x32_bf16(
                    af[m], bf[n], acc[m][n], 0, 0, 0);
    }

    // C/D layout (16x16x32): col = lane&15, row = (lane>>4)*4 + reg
    const int lg = lane >> 4;
#pragma unroll
    for (int m = 0; m < 4; ++m)
#pragma unroll
        for (int n = 0; n < 4; ++n) {
            const size_t colw = col0 + (wn << 6) + (n << 4) + lr;
#pragma unroll
            for (int j = 0; j < 4; ++j) {
                const size_t roww = row0 + (wm << 6) + (m << 4) + (lg << 2) + j;
                Z[roww * MDIM + colw] = acc[m][n][j];
            }
        }
}

// ---------------------------------------------------------------------------
// k4: z = fwht(z) / 64 * SV, in place on d_out. Same structure as k1.
__global__ __launch_bounds__(256) void fwht_out_kernel(
        float* __restrict__ z, const float* __restrict__ SV) {
    __shared__ float sh[4096];
    const int t = threadIdx.x;
    const size_t r = blockIdx.x;
    float4* row = (float4*)(z + (r << 12));
    const float4* sv4 = (const float4*)SV;

    float4 v[4];
#pragma unroll
    for (int s = 0; s < 4; ++s) v[s] = row[t + (s << 8)];
#pragma unroll
    for (int s = 0; s < 4; ++s) {
        bfly(v[s].x, v[s].y); bfly(v[s].z, v[s].w);   // h=1
        bfly(v[s].x, v[s].z); bfly(v[s].y, v[s].w);   // h=2
    }
    bfly4(v[0], v[1]); bfly4(v[2], v[3]);             // h=1024
    bfly4(v[0], v[2]); bfly4(v[1], v[3]);             // h=2048

#pragma unroll
    for (int s = 0; s < 4; ++s) ((float4*)sh)[t + (s << 8)] = v[s];

#pragma unroll
    for (int h = 4; h <= 512; h <<= 1) {
        __syncthreads();
#pragma unroll
        for (int s = 0; s < 8; ++s) {
            int p = t + (s << 8);
            int i = ((p & ~(h - 1)) << 1) | (p & (h - 1));
            float a = sh[i], b = sh[i + h];
            sh[i] = a + b; sh[i + h] = a - b;
        }
    }
    __syncthreads();

    const float sc = 0.015625f;  // 1/64
#pragma unroll
    for (int s = 0; s < 4; ++s) {
        float4 a = ((const float4*)sh)[t + (s << 8)];
        float4 u = sv4[t + (s << 8)];
        a.x = a.x * sc * u.x; a.y = a.y * sc * u.y;
        a.z = a.z * sc * u.z; a.w = a.w * sc * u.w;
        row[t + (s << 8)] = a;
    }
}

// ---------------------------------------------------------------------------
extern "C" void kernel_launch(void* const* d_in, const int* in_sizes, int n_in,
                              void* d_out, int out_size, void* d_ws, size_t ws_size,
                              hipStream_t stream) {
    const float* input  = (const float*)d_in[0];
    const int*   Qidxs  = (const int*)d_in[1];
    const float* cbvals = (const float*)d_in[2];
    const float* SU     = (const float*)d_in[3];
    const float* SV     = (const float*)d_in[4];
    const float* Wscale = (const float*)d_in[5];
    const float* A      = (const float*)d_in[6];
    const float* B      = (const float*)d_in[7];
    float* out = (float*)d_out;

    __hip_bfloat16* xbf = (__hip_bfloat16*)d_ws;
    __hip_bfloat16* wbf = (__hip_bfloat16*)((char*)d_ws + (size_t)T_ROWS * NDIM * 2);

    fwht_in_kernel<<<T_ROWS, 256, 0, stream>>>(input, SU, xbf);
    dequant_kernel<<<dim3(MDIM / 64, MDIM / 64), 256, 0, stream>>>(
        Qidxs, cbvals, Wscale, A, B, wbf);
    gemm_bt_kernel<<<(T_ROWS / 128) * (MDIM / 128), 256, 0, stream>>>(xbf, wbf, out);
    fwht_out_kernel<<<T_ROWS, 256, 0, stream>>>(out, SV);
}

// Round 2
// 391.478 us; speedup vs baseline: 1.4289x; 1.4289x over previous
//
#include <hip/hip_runtime.h>
#include <hip/hip_bf16.h>

// QuantizedLinear: T=8192 rows, N=K=4096, M=4096, RANK=64, CODESZ=8, CB=256.
// ws layout: x_bf16 [8192*4096] + W_eff bf16 [4096*4096] = 96 MiB.

typedef __attribute__((ext_vector_type(8))) short short8;
typedef __attribute__((ext_vector_type(4))) float f32x4;

#define T_ROWS 8192
#define NDIM   4096
#define MDIM   4096
#define NT     (NDIM / 64)   // 64 K-tiles of BK=64

// ---------------------------------------------------------------------------
// global -> LDS async copy, 16B/lane. LDS dest: wave-uniform base + lane*16.
__device__ __forceinline__ void gld_lds16(const void* g, void* lds_uniform) {
    __builtin_amdgcn_global_load_lds(
        (const __attribute__((address_space(1))) unsigned int*)(unsigned long long)(uintptr_t)g,
        (__attribute__((address_space(3))) unsigned int*)(unsigned int)(uintptr_t)lds_uniform,
        16, 0, 0);
}

#define FENCE asm volatile("" ::: "memory")
#define BAR   do { FENCE; __builtin_amdgcn_s_barrier(); FENCE; } while (0)
#define LGK0  do { asm volatile("s_waitcnt lgkmcnt(0)" ::: "memory"); \
                   __builtin_amdgcn_sched_barrier(0); } while (0)
#define VMC4  asm volatile("s_waitcnt vmcnt(4)" ::: "memory")
#define VMC0  asm volatile("s_waitcnt vmcnt(0)" ::: "memory")

__device__ __forceinline__ void bfly(float& a, float& b) {
    float s = a + b, d = a - b; a = s; b = d;
}
__device__ __forceinline__ void bfly4(float4& a, float4& b) {
    bfly(a.x, b.x); bfly(a.y, b.y); bfly(a.z, b.z); bfly(a.w, b.w);
}

// ---------------------------------------------------------------------------
// k1: x = fwht(input * SU) / 64, bf16 out. (unchanged from round 1)
__global__ __launch_bounds__(256) void fwht_in_kernel(
        const float* __restrict__ in, const float* __restrict__ SU,
        __hip_bfloat16* __restrict__ xout) {
    __shared__ float sh[4096];
    const int t = threadIdx.x;
    const size_t r = blockIdx.x;
    const float4* src = (const float4*)(in + (r << 12));
    const float4* su4 = (const float4*)SU;

    float4 v[4];
#pragma unroll
    for (int s = 0; s < 4; ++s) {
        float4 a = src[t + (s << 8)];
        float4 u = su4[t + (s << 8)];
        a.x *= u.x; a.y *= u.y; a.z *= u.z; a.w *= u.w;
        v[s] = a;
    }
#pragma unroll
    for (int s = 0; s < 4; ++s) {
        bfly(v[s].x, v[s].y); bfly(v[s].z, v[s].w);
        bfly(v[s].x, v[s].z); bfly(v[s].y, v[s].w);
    }
    bfly4(v[0], v[1]); bfly4(v[2], v[3]);
    bfly4(v[0], v[2]); bfly4(v[1], v[3]);

#pragma unroll
    for (int s = 0; s < 4; ++s) ((float4*)sh)[t + (s << 8)] = v[s];

#pragma unroll
    for (int h = 4; h <= 512; h <<= 1) {
        __syncthreads();
#pragma unroll
        for (int s = 0; s < 8; ++s) {
            int p = t + (s << 8);
            int i = ((p & ~(h - 1)) << 1) | (p & (h - 1));
            float a = sh[i], b = sh[i + h];
            sh[i] = a + b; sh[i + h] = a - b;
        }
    }
    __syncthreads();

    __hip_bfloat16* dst = xout + (r << 12);
    const float sc = 0.015625f;
#pragma unroll
    for (int s = 0; s < 4; ++s) {
        float4 a = ((const float4*)sh)[t + (s << 8)];
        union { __hip_bfloat16 h[4]; unsigned long long u; } pk;
        pk.h[0] = __float2bfloat16(a.x * sc);
        pk.h[1] = __float2bfloat16(a.y * sc);
        pk.h[2] = __float2bfloat16(a.z * sc);
        pk.h[3] = __float2bfloat16(a.w * sc);
        ((unsigned long long*)dst)[t + (s << 8)] = pk.u;
    }
}

// ---------------------------------------------------------------------------
// k2: W_eff = dequant + A@B, bf16. (unchanged from round 1)
__global__ __launch_bounds__(256) void dequant_kernel(
        const int* __restrict__ Qidxs, const float* __restrict__ cb,
        const float* __restrict__ Wscale, const float* __restrict__ A,
        const float* __restrict__ B, __hip_bfloat16* __restrict__ Weff) {
    __shared__ float At[64][68];
    __shared__ float Bs[64][68];
    __shared__ float cbs[2048];
    const int t = threadIdx.x;
    const int i0 = blockIdx.y * 64, j0 = blockIdx.x * 64;

    {
        const float* ga = A + (size_t)i0 * 64;
        const int r = t >> 2, kb = (t & 3) * 16;
#pragma unroll
        for (int j = 0; j < 16; ++j) At[kb + j][r] = ga[t * 16 + j];
        const int k = t >> 2, c0 = (t & 3) * 16;
        const float* gb = B + (size_t)k * NDIM + j0 + c0;
#pragma unroll
        for (int j = 0; j < 16; ++j) Bs[k][c0 + j] = gb[j];
#pragma unroll
        for (int j = 0; j < 8; ++j) cbs[t * 8 + j] = cb[t * 8 + j];
    }
    __syncthreads();

    const int ty = t >> 4, tx = t & 15;
    float acc[4][4];
#pragma unroll
    for (int a = 0; a < 4; ++a)
#pragma unroll
        for (int b = 0; b < 4; ++b) acc[a][b] = 0.f;

#pragma unroll 8
    for (int k = 0; k < 64; ++k) {
        const float4 av = *(const float4*)&At[k][ty * 4];
        const float4 bv = *(const float4*)&Bs[k][tx * 4];
        const float aa[4] = {av.x, av.y, av.z, av.w};
        const float bb[4] = {bv.x, bv.y, bv.z, bv.w};
#pragma unroll
        for (int ii = 0; ii < 4; ++ii)
#pragma unroll
            for (int jj = 0; jj < 4; ++jj) acc[ii][jj] += aa[ii] * bb[jj];
    }

    const float wsc = Wscale[0];
#pragma unroll
    for (int ii = 0; ii < 4; ++ii) {
        const int i = i0 + ty * 4 + ii;
        const int* qrow = Qidxs + (size_t)i * (NDIM / 8);
        union { __hip_bfloat16 h[4]; unsigned long long u; } pk;
#pragma unroll
        for (int jj = 0; jj < 4; ++jj) {
            const int j = j0 + tx * 4 + jj;
            const int idx = qrow[j >> 3];
            const float val = cbs[idx * 8 + (j & 7)] * wsc + acc[ii][jj];
            pk.h[jj] = __float2bfloat16(val);
        }
        *(unsigned long long*)&Weff[(size_t)i * NDIM + j0 + tx * 4] = pk.u;
    }
}

// ---------------------------------------------------------------------------
// k3: 256x256x(BK=64) bf16 NT GEMM, 8-phase schedule (T2+T3+T4+T5).
// 8 waves = 2M x 4N, per-wave C = 128x64 (acc[8][4] f32x4).
// LDS 128 KiB: [dbuf2][A/B][half2][128x64 bf16], XOR-swizzled (byte ^= (row&7)<<4)
// via pre-swizzled global source + swizzled ds_read (both-sides involution).
// Pipeline ledger (per K-tile kt, cur buf = kt&1):
//   ph0: read B all 8 + A m0,1 (12 ds_read); stage kt+1.A.h0 (other buf)
//   ph1: read A m2,3;                         stage kt+1.A.h1 (other buf)
//   ph2: read A m4,5;                         stage kt+2.B.h0 (cur buf; B reads
//        finished in ph0, double-gated by ph1 barriers)
//   ph3: read A m6,7;                         stage kt+2.B.h1 (cur buf)
//   boundary: vmcnt(4) (newest 4 in flight = kt+2.B) -> kt+1 fully staged;
//             vmcnt(0) for kt >= NT-2 (prefetch guards off). Then s_barrier.
__global__ __launch_bounds__(512, 2) void gemm256_kernel(
        const __hip_bfloat16* __restrict__ X, const __hip_bfloat16* __restrict__ W,
        float* __restrict__ Z) {
    __shared__ short smem[65536];   // 128 KiB

    const int b = blockIdx.x;                 // 512 blocks, 512 % 8 == 0
    const int swz = (b & 7) * 64 + (b >> 3);  // XCD-bijective
    const int bm = swz >> 4, bn = swz & 15;   // 32 x 16 tiles

    const int tid = threadIdx.x;
    const int lane = tid & 63, wid = tid >> 6;
    const int wm = wid >> 2, wn = wid & 3;
    const int lr = lane & 15, lk = lane >> 4;
    const int swb = (lr & 7) << 4;                       // read-side XOR (bytes)
    const int c0 = (((lk << 4)) ^ swb) >> 1;             // kk=0 col (elements)
    const int c1 = ((64 | (lk << 4)) ^ swb) >> 1;        // kk=1 col (elements)
    const int wbase = wid << 9;                          // wave's lds chunk (elems)

    // staging: thread covers row grow, 16B chunk at swizzled col scol
    const int grow = tid >> 3;
    const int scol = (((tid & 7) ^ (grow & 7)) << 3);    // pre-swizzled source col
    const __hip_bfloat16* gA = X + (size_t)(bm * 256 + grow) * NDIM + scol;
    const __hip_bfloat16* gB = W + (size_t)(bn * 256 + grow) * NDIM + scol;

#define LDSA(buf, h, q) (&smem[(buf) * 32768 + (h) * 8192 + (q) * 4096 + wbase])
#define LDSB(buf, h, q) (&smem[(buf) * 32768 + 16384 + (h) * 8192 + (q) * 4096 + wbase])
#define STA(kt, h, q) gld_lds16(gA + (size_t)((h) * 128 + (q) * 64) * NDIM + (kt) * 64, \
                                LDSA((kt) & 1, h, q))
#define STB(kt, h, q) gld_lds16(gB + (size_t)((h) * 128 + (q) * 64) * NDIM + (kt) * 64, \
                                LDSB((kt) & 1, h, q))

    f32x4 acc[8][4];
#pragma unroll
    for (int m = 0; m < 8; ++m)
#pragma unroll
        for (int n = 0; n < 4; ++n) acc[m][n] = 0.f;

    // prologue: kt0 full (A.h0,A.h1,B.h0,B.h1) + kt1.B (late-slot halves)
    STA(0, 0, 0); STA(0, 0, 1); STA(0, 1, 0); STA(0, 1, 1);
    STB(0, 0, 0); STB(0, 0, 1); STB(0, 1, 0); STB(0, 1, 1);
    STB(1, 0, 0); STB(1, 0, 1); STB(1, 1, 0); STB(1, 1, 1);
    VMC4;   // oldest 8 (kt0) done; kt1.B in flight
    BAR;

#define READ_A(M0) do { \
    aK0 = *(const short8*)&smem[aB + ((M0) * 16 + lr) * 64 + c0]; \
    aK1 = *(const short8*)&smem[aB + ((M0) * 16 + lr) * 64 + c1]; \
    bK0 = *(const short8*)&smem[aB + ((M0) * 16 + 16 + lr) * 64 + c0]; \
    bK1 = *(const short8*)&smem[aB + ((M0) * 16 + 16 + lr) * 64 + c1]; \
} while (0)

#define MFMA_PHASE(M0) do { \
    __builtin_amdgcn_s_setprio(1); \
    _Pragma("unroll") \
    for (int n = 0; n < 4; ++n) { \
        acc[M0][n]     = __builtin_amdgcn_mfma_f32_16x16x32_bf16(aK0, Bf[n][0], acc[M0][n], 0, 0, 0); \
        acc[M0][n]     = __builtin_amdgcn_mfma_f32_16x16x32_bf16(aK1, Bf[n][1], acc[M0][n], 0, 0, 0); \
        acc[M0 + 1][n] = __builtin_amdgcn_mfma_f32_16x16x32_bf16(bK0, Bf[n][0], acc[M0 + 1][n], 0, 0, 0); \
        acc[M0 + 1][n] = __builtin_amdgcn_mfma_f32_16x16x32_bf16(bK1, Bf[n][1], acc[M0 + 1][n], 0, 0, 0); \
    } \
    __builtin_amdgcn_s_setprio(0); \
    __builtin_amdgcn_sched_barrier(0); \
} while (0)

    for (int kt = 0; kt < NT; ++kt) {
        const int cur = (kt & 1) << 15;
        const int aB = cur + wm * 8192;                          // A half = wm
        const int bB = cur + 16384 + (wn >> 1) * 8192 + (wn & 1) * 4096;

        short8 Bf[4][2];
        short8 aK0, aK1, bK0, bK1;

        // ---- phase 0: B (8) + A m0,1 (4) reads; stage kt+1.A.h0
#pragma unroll
        for (int n = 0; n < 4; ++n) {
            const int rb = (n * 16 + lr) * 64;
            Bf[n][0] = *(const short8*)&smem[bB + rb + c0];
            Bf[n][1] = *(const short8*)&smem[bB + rb + c1];
        }
        READ_A(0);
        if (kt + 1 < NT) { STA(kt + 1, 0, 0); STA(kt + 1, 0, 1); }
        BAR; LGK0;
        MFMA_PHASE(0);
        BAR;

        // ---- phase 1: A m2,3; stage kt+1.A.h1
        READ_A(2);
        if (kt + 1 < NT) { STA(kt + 1, 1, 0); STA(kt + 1, 1, 1); }
        BAR; LGK0;
        MFMA_PHASE(2);
        BAR;

        // ---- phase 2: A m4,5; stage kt+2.B.h0
        READ_A(4);
        if (kt + 2 < NT) { STB(kt + 2, 0, 0); STB(kt + 2, 0, 1); }
        BAR; LGK0;
        MFMA_PHASE(4);
        BAR;

        // ---- phase 3: A m6,7; stage kt+2.B.h1
        READ_A(6);
        if (kt + 2 < NT) { STB(kt + 2, 1, 0); STB(kt + 2, 1, 1); }
        BAR; LGK0;
        MFMA_PHASE(6);
        if (kt < NT - 2) { VMC4; } else { VMC0; }
        BAR;
    }

    // epilogue: C/D layout col=lane&15, row=(lane>>4)*4+reg
    const size_t r0 = (size_t)bm * 256 + wm * 128 + (lk << 2);
    const size_t cb0 = (size_t)bn * 256 + wn * 64 + lr;
#pragma unroll
    for (int m = 0; m < 8; ++m)
#pragma unroll
        for (int n = 0; n < 4; ++n) {
            const size_t col = cb0 + n * 16;
#pragma unroll
            for (int j = 0; j < 4; ++j)
                Z[(r0 + m * 16 + j) * MDIM + col] = acc[m][n][j];
        }
}

// ---------------------------------------------------------------------------
// k4: z = fwht(z) / 64 * SV, in place. (unchanged from round 1)
__global__ __launch_bounds__(256) void fwht_out_kernel(
        float* __restrict__ z, const float* __restrict__ SV) {
    __shared__ float sh[4096];
    const int t = threadIdx.x;
    const size_t r = blockIdx.x;
    float4* row = (float4*)(z + (r << 12));
    const float4* sv4 = (const float4*)SV;

    float4 v[4];
#pragma unroll
    for (int s = 0; s < 4; ++s) v[s] = row[t + (s << 8)];
#pragma unroll
    for (int s = 0; s < 4; ++s) {
        bfly(v[s].x, v[s].y); bfly(v[s].z, v[s].w);
        bfly(v[s].x, v[s].z); bfly(v[s].y, v[s].w);
    }
    bfly4(v[0], v[1]); bfly4(v[2], v[3]);
    bfly4(v[0], v[2]); bfly4(v[1], v[3]);

#pragma unroll
    for (int s = 0; s < 4; ++s) ((float4*)sh)[t + (s << 8)] = v[s];

#pragma unroll
    for (int h = 4; h <= 512; h <<= 1) {
        __syncthreads();
#pragma unroll
        for (int s = 0; s < 8; ++s) {
            int p = t + (s << 8);
            int i = ((p & ~(h - 1)) << 1) | (p & (h - 1));
            float a = sh[i], b = sh[i + h];
            sh[i] = a + b; sh[i + h] = a - b;
        }
    }
    __syncthreads();

    const float sc = 0.015625f;
#pragma unroll
    for (int s = 0; s < 4; ++s) {
        float4 a = ((const float4*)sh)[t + (s << 8)];
        float4 u = sv4[t + (s << 8)];
        a.x = a.x * sc * u.x; a.y = a.y * sc * u.y;
        a.z = a.z * sc * u.z; a.w = a.w * sc * u.w;
        row[t + (s << 8)] = a;
    }
}

// ---------------------------------------------------------------------------
extern "C" void kernel_launch(void* const* d_in, const int* in_sizes, int n_in,
                              void* d_out, int out_size, void* d_ws, size_t ws_size,
                              hipStream_t stream) {
    const float* input  = (const float*)d_in[0];
    const int*   Qidxs  = (const int*)d_in[1];
    const float* cbvals = (const float*)d_in[2];
    const float* SU     = (const float*)d_in[3];
    const float* SV     = (const float*)d_in[4];
    const float* Wscale = (const float*)d_in[5];
    const float* A      = (const float*)d_in[6];
    const float* B      = (const float*)d_in[7];
    float* out = (float*)d_out;

    __hip_bfloat16* xbf = (__hip_bfloat16*)d_ws;
    __hip_bfloat16* wbf = (__hip_bfloat16*)((char*)d_ws + (size_t)T_ROWS * NDIM * 2);

    fwht_in_kernel<<<T_ROWS, 256, 0, stream>>>(input, SU, xbf);
    dequant_kernel<<<dim3(MDIM / 64, MDIM / 64), 256, 0, stream>>>(
        Qidxs, cbvals, Wscale, A, B, wbf);
    gemm256_kernel<<<(T_ROWS / 256) * (MDIM / 256), 512, 0, stream>>>(xbf, wbf, out);
    fwht_out_kernel<<<T_ROWS, 256, 0, stream>>>(out, SV);
}

// Round 3
// 385.532 us; speedup vs baseline: 1.4510x; 1.0154x over previous
//
#include <hip/hip_runtime.h>
#include <hip/hip_bf16.h>

// QuantizedLinear: T=8192 rows, N=K=4096, M=4096, RANK=64, CODESZ=8, CB=256.
// ws layout: x_bf16 [8192*4096] + W_eff bf16 [4096*4096] = 96 MiB.

typedef __attribute__((ext_vector_type(8))) short short8;
typedef __attribute__((ext_vector_type(4))) float f32x4;

#define T_ROWS 8192
#define NDIM   4096
#define MDIM   4096
#define NT     (NDIM / 64)   // 64 K-tiles of BK=64

// ---------------------------------------------------------------------------
// global -> LDS async copy, 16B/lane. LDS dest: wave-uniform base + lane*16.
__device__ __forceinline__ void gld_lds16(const void* g, void* lds_uniform) {
    __builtin_amdgcn_global_load_lds(
        (const __attribute__((address_space(1))) unsigned int*)(unsigned long long)(uintptr_t)g,
        (__attribute__((address_space(3))) unsigned int*)(unsigned int)(uintptr_t)lds_uniform,
        16, 0, 0);
}

__device__ __forceinline__ void bfly(float& a, float& b) {
    float s = a + b, d = a - b; a = s; b = d;
}
__device__ __forceinline__ void bfly4(float4& a, float4& b) {
    bfly(a.x, b.x); bfly(a.y, b.y); bfly(a.z, b.z); bfly(a.w, b.w);
}

// ---------------------------------------------------------------------------
// k1: x = fwht(input * SU) / 64, bf16 out. (unchanged)
__global__ __launch_bounds__(256) void fwht_in_kernel(
        const float* __restrict__ in, const float* __restrict__ SU,
        __hip_bfloat16* __restrict__ xout) {
    __shared__ float sh[4096];
    const int t = threadIdx.x;
    const size_t r = blockIdx.x;
    const float4* src = (const float4*)(in + (r << 12));
    const float4* su4 = (const float4*)SU;

    float4 v[4];
#pragma unroll
    for (int s = 0; s < 4; ++s) {
        float4 a = src[t + (s << 8)];
        float4 u = su4[t + (s << 8)];
        a.x *= u.x; a.y *= u.y; a.z *= u.z; a.w *= u.w;
        v[s] = a;
    }
#pragma unroll
    for (int s = 0; s < 4; ++s) {
        bfly(v[s].x, v[s].y); bfly(v[s].z, v[s].w);
        bfly(v[s].x, v[s].z); bfly(v[s].y, v[s].w);
    }
    bfly4(v[0], v[1]); bfly4(v[2], v[3]);
    bfly4(v[0], v[2]); bfly4(v[1], v[3]);

#pragma unroll
    for (int s = 0; s < 4; ++s) ((float4*)sh)[t + (s << 8)] = v[s];

#pragma unroll
    for (int h = 4; h <= 512; h <<= 1) {
        __syncthreads();
#pragma unroll
        for (int s = 0; s < 8; ++s) {
            int p = t + (s << 8);
            int i = ((p & ~(h - 1)) << 1) | (p & (h - 1));
            float a = sh[i], b = sh[i + h];
            sh[i] = a + b; sh[i + h] = a - b;
        }
    }
    __syncthreads();

    __hip_bfloat16* dst = xout + (r << 12);
    const float sc = 0.015625f;
#pragma unroll
    for (int s = 0; s < 4; ++s) {
        float4 a = ((const float4*)sh)[t + (s << 8)];
        union { __hip_bfloat16 h[4]; unsigned long long u; } pk;
        pk.h[0] = __float2bfloat16(a.x * sc);
        pk.h[1] = __float2bfloat16(a.y * sc);
        pk.h[2] = __float2bfloat16(a.z * sc);
        pk.h[3] = __float2bfloat16(a.w * sc);
        ((unsigned long long*)dst)[t + (s << 8)] = pk.u;
    }
}

// ---------------------------------------------------------------------------
// k2: W_eff = dequant + A@B, bf16. (unchanged)
__global__ __launch_bounds__(256) void dequant_kernel(
        const int* __restrict__ Qidxs, const float* __restrict__ cb,
        const float* __restrict__ Wscale, const float* __restrict__ A,
        const float* __restrict__ B, __hip_bfloat16* __restrict__ Weff) {
    __shared__ float At[64][68];
    __shared__ float Bs[64][68];
    __shared__ float cbs[2048];
    const int t = threadIdx.x;
    const int i0 = blockIdx.y * 64, j0 = blockIdx.x * 64;

    {
        const float* ga = A + (size_t)i0 * 64;
        const int r = t >> 2, kb = (t & 3) * 16;
#pragma unroll
        for (int j = 0; j < 16; ++j) At[kb + j][r] = ga[t * 16 + j];
        const int k = t >> 2, c0 = (t & 3) * 16;
        const float* gb = B + (size_t)k * NDIM + j0 + c0;
#pragma unroll
        for (int j = 0; j < 16; ++j) Bs[k][c0 + j] = gb[j];
#pragma unroll
        for (int j = 0; j < 8; ++j) cbs[t * 8 + j] = cb[t * 8 + j];
    }
    __syncthreads();

    const int ty = t >> 4, tx = t & 15;
    float acc[4][4];
#pragma unroll
    for (int a = 0; a < 4; ++a)
#pragma unroll
        for (int b = 0; b < 4; ++b) acc[a][b] = 0.f;

#pragma unroll 8
    for (int k = 0; k < 64; ++k) {
        const float4 av = *(const float4*)&At[k][ty * 4];
        const float4 bv = *(const float4*)&Bs[k][tx * 4];
        const float aa[4] = {av.x, av.y, av.z, av.w};
        const float bb[4] = {bv.x, bv.y, bv.z, bv.w};
#pragma unroll
        for (int ii = 0; ii < 4; ++ii)
#pragma unroll
            for (int jj = 0; jj < 4; ++jj) acc[ii][jj] += aa[ii] * bb[jj];
    }

    const float wsc = Wscale[0];
#pragma unroll
    for (int ii = 0; ii < 4; ++ii) {
        const int i = i0 + ty * 4 + ii;
        const int* qrow = Qidxs + (size_t)i * (NDIM / 8);
        union { __hip_bfloat16 h[4]; unsigned long long u; } pk;
#pragma unroll
        for (int jj = 0; jj < 4; ++jj) {
            const int j = j0 + tx * 4 + jj;
            const int idx = qrow[j >> 3];
            const float val = cbs[idx * 8 + (j & 7)] * wsc + acc[ii][jj];
            pk.h[jj] = __float2bfloat16(val);
        }
        *(unsigned long long*)&Weff[(size_t)i * NDIM + j0 + tx * 4] = pk.u;
    }
}

// ---------------------------------------------------------------------------
// k3: 256x256x(BK=64) bf16 NT GEMM — single-barrier interleaved schedule.
// 8 waves = 2M x 4N, per-wave C = 128x64 (acc[8][4] f32x4), 16x16x32 MFMA.
// B-fragments for tile kt are prefetched from LDS during tile kt-1 (regs),
// so each tile interleaves A-chunk ds_reads with MFMA clusters with only
// compiler-counted lgkmcnt waits; ONE s_barrier per K-tile.
// Per-tile ledger (entry: buf CUR holds kt data; outstanding vm = STB(kt+1)x4):
//   issue STA(kt+1)->!CUR.A (4), STB(kt+2)->CUR.B (4)    [12 outstanding]
//   RDA m0,m2; MFMA m0; RDA m4; MFMA m2; RDA m6
//   vmcnt(8): STB(kt+1) landed -> RDB BfNext from !CUR.B
//   MFMA m4; MFMA m6
//   lgkmcnt(0)  (all LDS reads done -> WAR vs next tile's STA/STB safe)
//   vmcnt(4)    (STA(kt+1) landed -> next tile's A ready)
//   s_barrier
// Tail: kt=62 (no STB, vmcnt mid 4, end 0), kt=63 (no stage/prefetch).
__global__ __launch_bounds__(512, 2) void gemm256_kernel(
        const __hip_bfloat16* __restrict__ X, const __hip_bfloat16* __restrict__ W,
        float* __restrict__ Z) {
    __shared__ short smem[65536];   // 128 KiB: [buf2][A 16K | B 16K elems]

    const int b = blockIdx.x;                 // 512 blocks, 512 % 8 == 0
    const int swz = (b & 7) * 64 + (b >> 3);  // XCD-bijective
    const int bm = swz >> 4, bn = swz & 15;   // 32 x 16 tiles

    const int tid = threadIdx.x;
    const int lane = tid & 63, wid = tid >> 6;
    const int wm = wid >> 2, wn = wid & 3;
    const int lr = lane & 15, lk = lane >> 4;
    const int swb = (lr & 7) << 4;                       // read-side XOR (bytes)
    const int c0 = (((lk << 4)) ^ swb) >> 1;             // kk=0 col (elements)
    const int c1 = ((64 | (lk << 4)) ^ swb) >> 1;        // kk=1 col (elements)
    const int wbase = wid << 9;

    const int grow = tid >> 3;
    const int scol = (((tid & 7) ^ (grow & 7)) << 3);    // pre-swizzled source col
    const __hip_bfloat16* gA = X + (size_t)(bm * 256 + grow) * NDIM + scol;
    const __hip_bfloat16* gB = W + (size_t)(bn * 256 + grow) * NDIM + scol;

#define STA2(OFS, H, Q, BUF) gld_lds16(gA + (size_t)(((H) * 128 + (Q) * 64) * NDIM) + (OFS), \
        &smem[(BUF) * 32768 + (H) * 8192 + (Q) * 4096 + wbase])
#define STB2(OFS, H, Q, BUF) gld_lds16(gB + (size_t)(((H) * 128 + (Q) * 64) * NDIM) + (OFS), \
        &smem[(BUF) * 32768 + 16384 + (H) * 8192 + (Q) * 4096 + wbase])
#define STAGE_A(OFS, BUF) do { STA2(OFS,0,0,BUF); STA2(OFS,0,1,BUF); \
                               STA2(OFS,1,0,BUF); STA2(OFS,1,1,BUF); } while (0)
#define STAGE_B(OFS, BUF) do { STB2(OFS,0,0,BUF); STB2(OFS,0,1,BUF); \
                               STB2(OFS,1,0,BUF); STB2(OFS,1,1,BUF); } while (0)

#define RDA(D0, D1, D2, D3, M0, AB) do { \
    D0 = *(const short8*)((AB) + ((M0) * 16 + lr) * 64 + c0); \
    D1 = *(const short8*)((AB) + ((M0) * 16 + lr) * 64 + c1); \
    D2 = *(const short8*)((AB) + ((M0) * 16 + 16 + lr) * 64 + c0); \
    D3 = *(const short8*)((AB) + ((M0) * 16 + 16 + lr) * 64 + c1); \
} while (0)

#define RDB(BARR, BUF) do { \
    const short* bB_ = smem + (BUF) * 32768 + 16384 + (wn * 64 + lr) * 64; \
    _Pragma("unroll") \
    for (int n = 0; n < 4; ++n) { \
        BARR[2 * n]     = *(const short8*)(bB_ + n * 1024 + c0); \
        BARR[2 * n + 1] = *(const short8*)(bB_ + n * 1024 + c1); \
    } \
} while (0)

#define MFMA2(A0, A1, E0, E1, M0, BF) do { \
    __builtin_amdgcn_s_setprio(1); \
    _Pragma("unroll") \
    for (int n = 0; n < 4; ++n) \
        acc[M0][n] = __builtin_amdgcn_mfma_f32_16x16x32_bf16(A0, BF[2 * n], acc[M0][n], 0, 0, 0); \
    _Pragma("unroll") \
    for (int n = 0; n < 4; ++n) \
        acc[(M0) + 1][n] = __builtin_amdgcn_mfma_f32_16x16x32_bf16(E0, BF[2 * n], acc[(M0) + 1][n], 0, 0, 0); \
    _Pragma("unroll") \
    for (int n = 0; n < 4; ++n) \
        acc[M0][n] = __builtin_amdgcn_mfma_f32_16x16x32_bf16(A1, BF[2 * n + 1], acc[M0][n], 0, 0, 0); \
    _Pragma("unroll") \
    for (int n = 0; n < 4; ++n) \
        acc[(M0) + 1][n] = __builtin_amdgcn_mfma_f32_16x16x32_bf16(E1, BF[2 * n + 1], acc[(M0) + 1][n], 0, 0, 0); \
    __builtin_amdgcn_s_setprio(0); \
} while (0)

#define TILE(CUR, BF, BN, DO_STA, DO_STB, DO_BN, VMMID, VMEND, DO_ENDBAR) do { \
    const short* aBase = smem + (CUR) * 32768 + wm * 8192; \
    if (DO_STA) STAGE_A(64, 1 - (CUR)); \
    if (DO_STB) STAGE_B(128, (CUR)); \
    RDA(xa0, xa1, xb0, xb1, 0, aBase); \
    RDA(ya0, ya1, yb0, yb1, 2, aBase); \
    MFMA2(xa0, xa1, xb0, xb1, 0, BF); \
    RDA(xa0, xa1, xb0, xb1, 4, aBase); \
    MFMA2(ya0, ya1, yb0, yb1, 2, BF); \
    RDA(ya0, ya1, yb0, yb1, 6, aBase); \
    if (DO_BN) { \
        asm volatile("s_waitcnt vmcnt(" #VMMID ")" ::: "memory"); \
        RDB(BN, 1 - (CUR)); \
    } \
    MFMA2(xa0, xa1, xb0, xb1, 4, BF); \
    MFMA2(ya0, ya1, yb0, yb1, 6, BF); \
    asm volatile("s_waitcnt lgkmcnt(0)" ::: "memory"); \
    asm volatile("s_waitcnt vmcnt(" #VMEND ")" ::: "memory"); \
    if (DO_ENDBAR) __builtin_amdgcn_s_barrier(); \
    gA += 64; gB += 64; \
} while (0)

    f32x4 acc[8][4];
#pragma unroll
    for (int m = 0; m < 8; ++m)
#pragma unroll
        for (int n = 0; n < 4; ++n) acc[m][n] = 0.f;

    short8 B0r[8], B1r[8];
    short8 xa0, xa1, xb0, xb1, ya0, ya1, yb0, yb1;

    // prologue: stage kt0 (A+B) + kt1.B; publish; prefetch Bf(0) to regs
    STAGE_A(0, 0);
    STAGE_B(0, 0);
    STAGE_B(64, 1);
    asm volatile("s_waitcnt vmcnt(4)" ::: "memory");   // kt0 resident; kt1.B in flight
    __builtin_amdgcn_s_barrier();
    RDB(B0r, 0);
    asm volatile("s_waitcnt lgkmcnt(0)" ::: "memory"); // B(0) reads done before any STB(2)
    __builtin_amdgcn_s_barrier();

    for (int i = 0; i < 31; ++i) {          // kt = 0..61
        TILE(0, B0r, B1r, 1, 1, 1, 8, 4, 1);
        TILE(1, B1r, B0r, 1, 1, 1, 8, 4, 1);
    }
    TILE(0, B0r, B1r, 1, 0, 1, 4, 0, 1);    // kt = 62: no STB; drain fully
    TILE(1, B1r, B0r, 0, 0, 0, 0, 0, 0);    // kt = 63: compute only

    // epilogue: C/D layout col=lane&15, row=(lane>>4)*4+reg
    const size_t r0 = (size_t)bm * 256 + wm * 128 + (lk << 2);
    const size_t cb0 = (size_t)bn * 256 + wn * 64 + lr;
#pragma unroll
    for (int m = 0; m < 8; ++m)
#pragma unroll
        for (int n = 0; n < 4; ++n) {
            const size_t col = cb0 + n * 16;
#pragma unroll
            for (int j = 0; j < 4; ++j)
                Z[(r0 + m * 16 + j) * MDIM + col] = acc[m][n][j];
        }
}

// ---------------------------------------------------------------------------
// k4: z = fwht(z) / 64 * SV, in place. (unchanged)
__global__ __launch_bounds__(256) void fwht_out_kernel(
        float* __restrict__ z, const float* __restrict__ SV) {
    __shared__ float sh[4096];
    const int t = threadIdx.x;
    const size_t r = blockIdx.x;
    float4* row = (float4*)(z + (r << 12));
    const float4* sv4 = (const float4*)SV;

    float4 v[4];
#pragma unroll
    for (int s = 0; s < 4; ++s) v[s] = row[t + (s << 8)];
#pragma unroll
    for (int s = 0; s < 4; ++s) {
        bfly(v[s].x, v[s].y); bfly(v[s].z, v[s].w);
        bfly(v[s].x, v[s].z); bfly(v[s].y, v[s].w);
    }
    bfly4(v[0], v[1]); bfly4(v[2], v[3]);
    bfly4(v[0], v[2]); bfly4(v[1], v[3]);

#pragma unroll
    for (int s = 0; s < 4; ++s) ((float4*)sh)[t + (s << 8)] = v[s];

#pragma unroll
    for (int h = 4; h <= 512; h <<= 1) {
        __syncthreads();
#pragma unroll
        for (int s = 0; s < 8; ++s) {
            int p = t + (s << 8);
            int i = ((p & ~(h - 1)) << 1) | (p & (h - 1));
            float a = sh[i], b = sh[i + h];
            sh[i] = a + b; sh[i + h] = a - b;
        }
    }
    __syncthreads();

    const float sc = 0.015625f;
#pragma unroll
    for (int s = 0; s < 4; ++s) {
        float4 a = ((const float4*)sh)[t + (s << 8)];
        float4 u = sv4[t + (s << 8)];
        a.x = a.x * sc * u.x; a.y = a.y * sc * u.y;
        a.z = a.z * sc * u.z; a.w = a.w * sc * u.w;
        row[t + (s << 8)] = a;
    }
}

// ---------------------------------------------------------------------------
extern "C" void kernel_launch(void* const* d_in, const int* in_sizes, int n_in,
                              void* d_out, int out_size, void* d_ws, size_t ws_size,
                              hipStream_t stream) {
    const float* input  = (const float*)d_in[0];
    const int*   Qidxs  = (const int*)d_in[1];
    const float* cbvals = (const float*)d_in[2];
    const float* SU     = (const float*)d_in[3];
    const float* SV     = (const float*)d_in[4];
    const float* Wscale = (const float*)d_in[5];
    const float* A      = (const float*)d_in[6];
    const float* B      = (const float*)d_in[7];
    float* out = (float*)d_out;

    __hip_bfloat16* xbf = (__hip_bfloat16*)d_ws;
    __hip_bfloat16* wbf = (__hip_bfloat16*)((char*)d_ws + (size_t)T_ROWS * NDIM * 2);

    fwht_in_kernel<<<T_ROWS, 256, 0, stream>>>(input, SU, xbf);
    dequant_kernel<<<dim3(MDIM / 64, MDIM / 64), 256, 0, stream>>>(
        Qidxs, cbvals, Wscale, A, B, wbf);
    gemm256_kernel<<<(T_ROWS / 256) * (MDIM / 256), 512, 0, stream>>>(xbf, wbf, out);
    fwht_out_kernel<<<T_ROWS, 256, 0, stream>>>(out, SV);
}

// Round 4
// 379.542 us; speedup vs baseline: 1.4739x; 1.0158x over previous
//
#include <hip/hip_runtime.h>
#include <hip/hip_bf16.h>

// QuantizedLinear: T=8192 rows, N=K=4096, M=4096, RANK=64, CODESZ=8, CB=256.
// ws layout: x_bf16 [8192*4096] + W_eff bf16 [4096*4096] = 96 MiB.

typedef __attribute__((ext_vector_type(8))) short short8;
typedef __attribute__((ext_vector_type(4))) float f32x4;

#define T_ROWS 8192
#define NDIM   4096
#define MDIM   4096
#define NT     (NDIM / 64)   // 64 K-tiles of BK=64

// ---------------------------------------------------------------------------
// global -> LDS async copy, 16B/lane. LDS dest: wave-uniform base + lane*16.
__device__ __forceinline__ void gld_lds16(const void* g, void* lds_uniform) {
    __builtin_amdgcn_global_load_lds(
        (const __attribute__((address_space(1))) unsigned int*)(unsigned long long)(uintptr_t)g,
        (__attribute__((address_space(3))) unsigned int*)(unsigned int)(uintptr_t)lds_uniform,
        16, 0, 0);
}

__device__ __forceinline__ void bfly(float& a, float& b) {
    float s = a + b, d = a - b; a = s; b = d;
}

// ---------------------------------------------------------------------------
// 3-phase in-register FWHT-4096: thread t owns, per phase,
//   A: idx = t*16 + j      (bits 0-3 in regs)
//   B: idx = j*16 + (t&15) + (t>>4)*256   (bits 4-7 in regs)
//   C: idx = j*256 + t     (bits 8-11 in regs)
// LDS padded addr(idx) = idx + (idx>>4); 2 syncthreads total.
__device__ __forceinline__ void fwht16(float* v) {
#pragma unroll
    for (int h = 1; h <= 8; h <<= 1)
#pragma unroll
        for (int j = 0; j < 16; ++j)
            if (!(j & h)) bfly(v[j], v[j | h]);
}

// k1: x = fwht(input * SU) / 64, bf16 out.
__global__ __launch_bounds__(256) void fwht_in_kernel(
        const float* __restrict__ in, const float* __restrict__ SU,
        __hip_bfloat16* __restrict__ xout) {
    __shared__ float sh[4352];
    const int t = threadIdx.x;
    const size_t r = blockIdx.x;
    float v[16];
    {
        const float4* s4 = (const float4*)(in + (r << 12) + t * 16);
        const float4* u4 = (const float4*)(SU + t * 16);
#pragma unroll
        for (int q = 0; q < 4; ++q) {
            float4 a = s4[q], u = u4[q];
            v[4 * q + 0] = a.x * u.x; v[4 * q + 1] = a.y * u.y;
            v[4 * q + 2] = a.z * u.z; v[4 * q + 3] = a.w * u.w;
        }
    }
    fwht16(v);                                   // bits 0-3
#pragma unroll
    for (int j = 0; j < 16; ++j) sh[17 * t + j] = v[j];
    __syncthreads();
    const int baseB = (t & 15) + 272 * (t >> 4);
#pragma unroll
    for (int j = 0; j < 16; ++j) v[j] = sh[baseB + 17 * j];
    fwht16(v);                                   // bits 4-7
#pragma unroll
    for (int j = 0; j < 16; ++j) sh[baseB + 17 * j] = v[j];
    __syncthreads();
    const int baseC = t + (t >> 4);
#pragma unroll
    for (int j = 0; j < 16; ++j) v[j] = sh[baseC + 272 * j];
    fwht16(v);                                   // bits 8-11
    __hip_bfloat16* dst = xout + (r << 12);
#pragma unroll
    for (int j = 0; j < 16; ++j)
        dst[(j << 8) + t] = __float2bfloat16(v[j] * 0.015625f);
}

// k4: z = fwht(z) / 64 * SV, in place (f32).
__global__ __launch_bounds__(256) void fwht_out_kernel(
        float* __restrict__ z, const float* __restrict__ SV) {
    __shared__ float sh[4352];
    const int t = threadIdx.x;
    const size_t r = blockIdx.x;
    float* row = z + (r << 12);
    float v[16];
    {
        const float4* s4 = (const float4*)(row + t * 16);
#pragma unroll
        for (int q = 0; q < 4; ++q) {
            float4 a = s4[q];
            v[4 * q + 0] = a.x; v[4 * q + 1] = a.y;
            v[4 * q + 2] = a.z; v[4 * q + 3] = a.w;
        }
    }
    fwht16(v);
#pragma unroll
    for (int j = 0; j < 16; ++j) sh[17 * t + j] = v[j];
    __syncthreads();
    const int baseB = (t & 15) + 272 * (t >> 4);
#pragma unroll
    for (int j = 0; j < 16; ++j) v[j] = sh[baseB + 17 * j];
    fwht16(v);
#pragma unroll
    for (int j = 0; j < 16; ++j) sh[baseB + 17 * j] = v[j];
    __syncthreads();
    const int baseC = t + (t >> 4);
#pragma unroll
    for (int j = 0; j < 16; ++j) v[j] = sh[baseC + 272 * j];
    fwht16(v);
#pragma unroll
    for (int j = 0; j < 16; ++j)
        row[(j << 8) + t] = v[j] * 0.015625f * SV[(j << 8) + t];
}

// ---------------------------------------------------------------------------
// k2: W_eff = dequant + A@B, bf16. (unchanged)
__global__ __launch_bounds__(256) void dequant_kernel(
        const int* __restrict__ Qidxs, const float* __restrict__ cb,
        const float* __restrict__ Wscale, const float* __restrict__ A,
        const float* __restrict__ B, __hip_bfloat16* __restrict__ Weff) {
    __shared__ float At[64][68];
    __shared__ float Bs[64][68];
    __shared__ float cbs[2048];
    const int t = threadIdx.x;
    const int i0 = blockIdx.y * 64, j0 = blockIdx.x * 64;

    {
        const float* ga = A + (size_t)i0 * 64;
        const int r = t >> 2, kb = (t & 3) * 16;
#pragma unroll
        for (int j = 0; j < 16; ++j) At[kb + j][r] = ga[t * 16 + j];
        const int k = t >> 2, c0 = (t & 3) * 16;
        const float* gb = B + (size_t)k * NDIM + j0 + c0;
#pragma unroll
        for (int j = 0; j < 16; ++j) Bs[k][c0 + j] = gb[j];
#pragma unroll
        for (int j = 0; j < 8; ++j) cbs[t * 8 + j] = cb[t * 8 + j];
    }
    __syncthreads();

    const int ty = t >> 4, tx = t & 15;
    float acc[4][4];
#pragma unroll
    for (int a = 0; a < 4; ++a)
#pragma unroll
        for (int b = 0; b < 4; ++b) acc[a][b] = 0.f;

#pragma unroll 8
    for (int k = 0; k < 64; ++k) {
        const float4 av = *(const float4*)&At[k][ty * 4];
        const float4 bv = *(const float4*)&Bs[k][tx * 4];
        const float aa[4] = {av.x, av.y, av.z, av.w};
        const float bb[4] = {bv.x, bv.y, bv.z, bv.w};
#pragma unroll
        for (int ii = 0; ii < 4; ++ii)
#pragma unroll
            for (int jj = 0; jj < 4; ++jj) acc[ii][jj] += aa[ii] * bb[jj];
    }

    const float wsc = Wscale[0];
#pragma unroll
    for (int ii = 0; ii < 4; ++ii) {
        const int i = i0 + ty * 4 + ii;
        const int* qrow = Qidxs + (size_t)i * (NDIM / 8);
        union { __hip_bfloat16 h[4]; unsigned long long u; } pk;
#pragma unroll
        for (int jj = 0; jj < 4; ++jj) {
            const int j = j0 + tx * 4 + jj;
            const int idx = qrow[j >> 3];
            const float val = cbs[idx * 8 + (j & 7)] * wsc + acc[ii][jj];
            pk.h[jj] = __float2bfloat16(val);
        }
        *(unsigned long long*)&Weff[(size_t)i * NDIM + j0 + tx * 4] = pk.u;
    }
}

// ---------------------------------------------------------------------------
// k3: 256x256x(BK=64) bf16 NT GEMM — cross-barrier register prefetch.
// Per tile kt (steady; entry: BF=Bf(kt), AFP(p0..p3)=A(kt).m0, 4 vm outstanding):
//   STA(kt+1)->!CUR.A x4 [8]; STB(kt+2)->CUR.B x4 [12]
//   RDA m2->T; MFMA m0(AFP,BF)   <- matrix starts immediately, no start bubble
//   RDA m4->AFP; MFMA m2(T)
//   RDA m6->T;  MFMA m4(AFP)
//   vmcnt(4); s_barrier          <- STA(kt+1)+STB(kt+1) landed BLOCK-WIDE
//   RDB BN<-!CUR.B (Bf(kt+1)); RDA AFP<-!CUR.A m0 (A(kt+1).m0)
//   MFMA m6(T)                   <- overlaps prefetch-read latency
//   lgkmcnt(0); s_barrier        <- WAR: CUR reads done before next tile's stores
__global__ __launch_bounds__(512, 2) void gemm256_kernel(
        const __hip_bfloat16* __restrict__ X, const __hip_bfloat16* __restrict__ W,
        float* __restrict__ Z) {
    __shared__ short smem[65536];   // 128 KiB: [buf2][A 16K | B 16K elems]

    const int b = blockIdx.x;                 // 512 blocks, 512 % 8 == 0
    const int swz = (b & 7) * 64 + (b >> 3);  // XCD-bijective
    const int bm = swz >> 4, bn = swz & 15;   // 32 x 16 tiles

    const int tid = threadIdx.x;
    const int lane = tid & 63, wid = tid >> 6;
    const int wm = wid >> 2, wn = wid & 3;
    const int lr = lane & 15, lk = lane >> 4;
    const int swb = (lr & 7) << 4;                       // read-side XOR (bytes)
    const int c0 = (((lk << 4)) ^ swb) >> 1;             // kk=0 col (elements)
    const int c1 = ((64 | (lk << 4)) ^ swb) >> 1;        // kk=1 col (elements)
    const int wbase = wid << 9;

    const int grow = tid >> 3;
    const int scol = (((tid & 7) ^ (grow & 7)) << 3);    // pre-swizzled source col
    const __hip_bfloat16* gA = X + (size_t)(bm * 256 + grow) * NDIM + scol;
    const __hip_bfloat16* gB = W + (size_t)(bn * 256 + grow) * NDIM + scol;

#define STA2(OFS, H, Q, BUF) gld_lds16(gA + (size_t)(((H) * 128 + (Q) * 64) * NDIM) + (OFS), \
        &smem[(BUF) * 32768 + (H) * 8192 + (Q) * 4096 + wbase])
#define STB2(OFS, H, Q, BUF) gld_lds16(gB + (size_t)(((H) * 128 + (Q) * 64) * NDIM) + (OFS), \
        &smem[(BUF) * 32768 + 16384 + (H) * 8192 + (Q) * 4096 + wbase])
#define STAGE_A(OFS, BUF) do { STA2(OFS,0,0,BUF); STA2(OFS,0,1,BUF); \
                               STA2(OFS,1,0,BUF); STA2(OFS,1,1,BUF); } while (0)
#define STAGE_B(OFS, BUF) do { STB2(OFS,0,0,BUF); STB2(OFS,0,1,BUF); \
                               STB2(OFS,1,0,BUF); STB2(OFS,1,1,BUF); } while (0)

#define RDA(D0, D1, D2, D3, M0, AB) do { \
    D0 = *(const short8*)((AB) + ((M0) * 16 + lr) * 64 + c0); \
    D1 = *(const short8*)((AB) + ((M0) * 16 + lr) * 64 + c1); \
    D2 = *(const short8*)((AB) + ((M0) * 16 + 16 + lr) * 64 + c0); \
    D3 = *(const short8*)((AB) + ((M0) * 16 + 16 + lr) * 64 + c1); \
} while (0)

#define RDB(BARR, BUF) do { \
    const short* bB_ = smem + (BUF) * 32768 + 16384 + (wn * 64 + lr) * 64; \
    _Pragma("unroll") \
    for (int n = 0; n < 4; ++n) { \
        BARR[2 * n]     = *(const short8*)(bB_ + n * 1024 + c0); \
        BARR[2 * n + 1] = *(const short8*)(bB_ + n * 1024 + c1); \
    } \
} while (0)

#define MFMA2(A0, A1, E0, E1, M0, BF) do { \
    __builtin_amdgcn_s_setprio(1); \
    _Pragma("unroll") \
    for (int n = 0; n < 4; ++n) \
        acc[M0][n] = __builtin_amdgcn_mfma_f32_16x16x32_bf16(A0, BF[2 * n], acc[M0][n], 0, 0, 0); \
    _Pragma("unroll") \
    for (int n = 0; n < 4; ++n) \
        acc[(M0) + 1][n] = __builtin_amdgcn_mfma_f32_16x16x32_bf16(E0, BF[2 * n], acc[(M0) + 1][n], 0, 0, 0); \
    _Pragma("unroll") \
    for (int n = 0; n < 4; ++n) \
        acc[M0][n] = __builtin_amdgcn_mfma_f32_16x16x32_bf16(A1, BF[2 * n + 1], acc[M0][n], 0, 0, 0); \
    _Pragma("unroll") \
    for (int n = 0; n < 4; ++n) \
        acc[(M0) + 1][n] = __builtin_amdgcn_mfma_f32_16x16x32_bf16(E1, BF[2 * n + 1], acc[(M0) + 1][n], 0, 0, 0); \
    __builtin_amdgcn_s_setprio(0); \
} while (0)

#define TILE(CUR, BF, BN, DO_STA, DO_STB, DO_PF, VMMID, LAST) do { \
    const short* aBase = smem + (CUR) * 32768 + wm * 8192; \
    if (DO_STA) STAGE_A(64, 1 - (CUR)); \
    if (DO_STB) STAGE_B(128, (CUR)); \
    RDA(t0, t1, t2, t3, 2, aBase); \
    MFMA2(p0, p1, p2, p3, 0, BF); \
    RDA(p0, p1, p2, p3, 4, aBase); \
    MFMA2(t0, t1, t2, t3, 2, BF); \
    RDA(t0, t1, t2, t3, 6, aBase); \
    MFMA2(p0, p1, p2, p3, 4, BF); \
    if (DO_PF) { \
        asm volatile("s_waitcnt vmcnt(" #VMMID ")" ::: "memory"); \
        __builtin_amdgcn_s_barrier(); \
        RDB(BN, 1 - (CUR)); \
        RDA(p0, p1, p2, p3, 0, smem + (1 - (CUR)) * 32768 + wm * 8192); \
        __builtin_amdgcn_sched_barrier(0); \
    } \
    MFMA2(t0, t1, t2, t3, 6, BF); \
    if (!(LAST)) { \
        asm volatile("s_waitcnt lgkmcnt(0)" ::: "memory"); \
        __builtin_amdgcn_s_barrier(); \
    } \
    gA += 64; gB += 64; \
} while (0)

    f32x4 acc[8][4];
#pragma unroll
    for (int m = 0; m < 8; ++m)
#pragma unroll
        for (int n = 0; n < 4; ++n) acc[m][n] = 0.f;

    short8 B0r[8], B1r[8];
    short8 p0, p1, p2, p3, t0, t1, t2, t3;

    // prologue: stage kt0 (A+B) + kt1.B; publish; prefetch Bf(0) + A(0).m0
    STAGE_A(0, 0);
    STAGE_B(0, 0);
    STAGE_B(64, 1);
    asm volatile("s_waitcnt vmcnt(4)" ::: "memory");   // kt0 resident; kt1.B in flight
    __builtin_amdgcn_s_barrier();
    RDB(B0r, 0);
    RDA(p0, p1, p2, p3, 0, smem + wm * 8192);
    asm volatile("s_waitcnt lgkmcnt(0)" ::: "memory");
    __builtin_amdgcn_s_barrier();

    for (int i = 0; i < 31; ++i) {              // kt = 0..61
        TILE(0, B0r, B1r, 1, 1, 1, 4, 0);
        TILE(1, B1r, B0r, 1, 1, 1, 4, 0);
    }
    TILE(0, B0r, B1r, 1, 0, 1, 0, 0);           // kt = 62: no STB; full drain
    TILE(1, B1r, B0r, 0, 0, 0, 0, 1);           // kt = 63: compute only

    // epilogue: C/D layout col=lane&15, row=(lane>>4)*4+reg
    const size_t r0 = (size_t)bm * 256 + wm * 128 + (lk << 2);
    const size_t cb0 = (size_t)bn * 256 + wn * 64 + lr;
#pragma unroll
    for (int m = 0; m < 8; ++m)
#pragma unroll
        for (int n = 0; n < 4; ++n) {
            const size_t col = cb0 + n * 16;
#pragma unroll
            for (int j = 0; j < 4; ++j)
                Z[(r0 + m * 16 + j) * MDIM + col] = acc[m][n][j];
        }
}

// ---------------------------------------------------------------------------
extern "C" void kernel_launch(void* const* d_in, const int* in_sizes, int n_in,
                              void* d_out, int out_size, void* d_ws, size_t ws_size,
                              hipStream_t stream) {
    const float* input  = (const float*)d_in[0];
    const int*   Qidxs  = (const int*)d_in[1];
    const float* cbvals = (const float*)d_in[2];
    const float* SU     = (const float*)d_in[3];
    const float* SV     = (const float*)d_in[4];
    const float* Wscale = (const float*)d_in[5];
    const float* A      = (const float*)d_in[6];
    const float* B      = (const float*)d_in[7];
    float* out = (float*)d_out;

    __hip_bfloat16* xbf = (__hip_bfloat16*)d_ws;
    __hip_bfloat16* wbf = (__hip_bfloat16*)((char*)d_ws + (size_t)T_ROWS * NDIM * 2);

    fwht_in_kernel<<<T_ROWS, 256, 0, stream>>>(input, SU, xbf);
    dequant_kernel<<<dim3(MDIM / 64, MDIM / 64), 256, 0, stream>>>(
        Qidxs, cbvals, Wscale, A, B, wbf);
    gemm256_kernel<<<(T_ROWS / 256) * (MDIM / 256), 512, 0, stream>>>(xbf, wbf, out);
    fwht_out_kernel<<<T_ROWS, 256, 0, stream>>>(out, SV);
}

// Round 5
// 356.873 us; speedup vs baseline: 1.5675x; 1.0635x over previous
//
#include <hip/hip_runtime.h>
#include <hip/hip_bf16.h>

// QuantizedLinear: T=8192 rows, N=K=4096, M=4096, RANK=64, CODESZ=8, CB=256.
// ws layout: x_bf16 [8192*4096] + W_eff bf16 [4096*4096] = 96 MiB.

typedef __attribute__((ext_vector_type(8))) short short8;
typedef __attribute__((ext_vector_type(4))) float f32x4;

#define T_ROWS 8192
#define NDIM   4096
#define MDIM   4096
#define NT     (NDIM / 64)   // 64 K-tiles of BK=64

// ---------------------------------------------------------------------------
// global -> LDS async copy, 16B/lane. LDS dest: wave-uniform base + lane*16.
__device__ __forceinline__ void gld_lds16(const void* g, void* lds_uniform) {
    __builtin_amdgcn_global_load_lds(
        (const __attribute__((address_space(1))) unsigned int*)(unsigned long long)(uintptr_t)g,
        (__attribute__((address_space(3))) unsigned int*)(unsigned int)(uintptr_t)lds_uniform,
        16, 0, 0);
}

__device__ __forceinline__ void bfly(float& a, float& b) {
    float s = a + b, d = a - b; a = s; b = d;
}

// ---------------------------------------------------------------------------
// 3-phase in-register FWHT-4096 (16 elems/thread, 2 syncthreads).
__device__ __forceinline__ void fwht16(float* v) {
#pragma unroll
    for (int h = 1; h <= 8; h <<= 1)
#pragma unroll
        for (int j = 0; j < 16; ++j)
            if (!(j & h)) bfly(v[j], v[j | h]);
}

// k1: x = fwht(input * SU) / 64, bf16 out.
__global__ __launch_bounds__(256) void fwht_in_kernel(
        const float* __restrict__ in, const float* __restrict__ SU,
        __hip_bfloat16* __restrict__ xout) {
    __shared__ float sh[4352];
    const int t = threadIdx.x;
    const size_t r = blockIdx.x;
    float v[16];
    {
        const float4* s4 = (const float4*)(in + (r << 12) + t * 16);
        const float4* u4 = (const float4*)(SU + t * 16);
#pragma unroll
        for (int q = 0; q < 4; ++q) {
            float4 a = s4[q], u = u4[q];
            v[4 * q + 0] = a.x * u.x; v[4 * q + 1] = a.y * u.y;
            v[4 * q + 2] = a.z * u.z; v[4 * q + 3] = a.w * u.w;
        }
    }
    fwht16(v);                                   // bits 0-3
#pragma unroll
    for (int j = 0; j < 16; ++j) sh[17 * t + j] = v[j];
    __syncthreads();
    const int baseB = (t & 15) + 272 * (t >> 4);
#pragma unroll
    for (int j = 0; j < 16; ++j) v[j] = sh[baseB + 17 * j];
    fwht16(v);                                   // bits 4-7
#pragma unroll
    for (int j = 0; j < 16; ++j) sh[baseB + 17 * j] = v[j];
    __syncthreads();
    const int baseC = t + (t >> 4);
#pragma unroll
    for (int j = 0; j < 16; ++j) v[j] = sh[baseC + 272 * j];
    fwht16(v);                                   // bits 8-11
    __hip_bfloat16* dst = xout + (r << 12);
#pragma unroll
    for (int j = 0; j < 16; ++j)
        dst[(j << 8) + t] = __float2bfloat16(v[j] * 0.015625f);
}

// k4: z = fwht(z) / 64 * SV, in place (f32).
__global__ __launch_bounds__(256) void fwht_out_kernel(
        float* __restrict__ z, const float* __restrict__ SV) {
    __shared__ float sh[4352];
    const int t = threadIdx.x;
    const size_t r = blockIdx.x;
    float* row = z + (r << 12);
    float v[16];
    {
        const float4* s4 = (const float4*)(row + t * 16);
#pragma unroll
        for (int q = 0; q < 4; ++q) {
            float4 a = s4[q];
            v[4 * q + 0] = a.x; v[4 * q + 1] = a.y;
            v[4 * q + 2] = a.z; v[4 * q + 3] = a.w;
        }
    }
    fwht16(v);
#pragma unroll
    for (int j = 0; j < 16; ++j) sh[17 * t + j] = v[j];
    __syncthreads();
    const int baseB = (t & 15) + 272 * (t >> 4);
#pragma unroll
    for (int j = 0; j < 16; ++j) v[j] = sh[baseB + 17 * j];
    fwht16(v);
#pragma unroll
    for (int j = 0; j < 16; ++j) sh[baseB + 17 * j] = v[j];
    __syncthreads();
    const int baseC = t + (t >> 4);
#pragma unroll
    for (int j = 0; j < 16; ++j) v[j] = sh[baseC + 272 * j];
    fwht16(v);
#pragma unroll
    for (int j = 0; j < 16; ++j)
        row[(j << 8) + t] = v[j] * 0.015625f * SV[(j << 8) + t];
}

// ---------------------------------------------------------------------------
// k2: W_eff = dequant + A@B, bf16. (unchanged)
__global__ __launch_bounds__(256) void dequant_kernel(
        const int* __restrict__ Qidxs, const float* __restrict__ cb,
        const float* __restrict__ Wscale, const float* __restrict__ A,
        const float* __restrict__ B, __hip_bfloat16* __restrict__ Weff) {
    __shared__ float At[64][68];
    __shared__ float Bs[64][68];
    __shared__ float cbs[2048];
    const int t = threadIdx.x;
    const int i0 = blockIdx.y * 64, j0 = blockIdx.x * 64;

    {
        const float* ga = A + (size_t)i0 * 64;
        const int r = t >> 2, kb = (t & 3) * 16;
#pragma unroll
        for (int j = 0; j < 16; ++j) At[kb + j][r] = ga[t * 16 + j];
        const int k = t >> 2, c0 = (t & 3) * 16;
        const float* gb = B + (size_t)k * NDIM + j0 + c0;
#pragma unroll
        for (int j = 0; j < 16; ++j) Bs[k][c0 + j] = gb[j];
#pragma unroll
        for (int j = 0; j < 8; ++j) cbs[t * 8 + j] = cb[t * 8 + j];
    }
    __syncthreads();

    const int ty = t >> 4, tx = t & 15;
    float acc[4][4];
#pragma unroll
    for (int a = 0; a < 4; ++a)
#pragma unroll
        for (int b = 0; b < 4; ++b) acc[a][b] = 0.f;

#pragma unroll 8
    for (int k = 0; k < 64; ++k) {
        const float4 av = *(const float4*)&At[k][ty * 4];
        const float4 bv = *(const float4*)&Bs[k][tx * 4];
        const float aa[4] = {av.x, av.y, av.z, av.w};
        const float bb[4] = {bv.x, bv.y, bv.z, bv.w};
#pragma unroll
        for (int ii = 0; ii < 4; ++ii)
#pragma unroll
            for (int jj = 0; jj < 4; ++jj) acc[ii][jj] += aa[ii] * bb[jj];
    }

    const float wsc = Wscale[0];
#pragma unroll
    for (int ii = 0; ii < 4; ++ii) {
        const int i = i0 + ty * 4 + ii;
        const int* qrow = Qidxs + (size_t)i * (NDIM / 8);
        union { __hip_bfloat16 h[4]; unsigned long long u; } pk;
#pragma unroll
        for (int jj = 0; jj < 4; ++jj) {
            const int j = j0 + tx * 4 + jj;
            const int idx = qrow[j >> 3];
            const float val = cbs[idx * 8 + (j & 7)] * wsc + acc[ii][jj];
            pk.h[jj] = __float2bfloat16(val);
        }
        *(unsigned long long*)&Weff[(size_t)i * NDIM + j0 + tx * 4] = pk.u;
    }
}

// ---------------------------------------------------------------------------
// k3: 256x256x(BK=64) bf16 NT GEMM — single barrier/tile, NO setprio.
// Sound pipeline (one barrier per tile):
//   tile kt entry (after barrier): ALL loads issued at tiles <= kt-1 are
//   block-wide visible (end-of-tile vmcnt(0) precedes every barrier, and
//   those loads are >= 1 full tile old => the drain is ~free).
//   issue STA(kt+1)->!CUR.A, STB(kt+2)->CUR.B
//   RDA m0,m2; MFMA m0; RDA m4; MFMA m2; RDA m6;
//   RDB Bf(kt+1) <- !CUR.B   (sound: written by STB issued at kt-1)
//   MFMA m4; MFMA m6         (RDB latency hides under these)
//   lgkmcnt(0); vmcnt(0); s_barrier
// No setprio: with 2 lockstep waves/SIMD, prio-boosting the MFMA wave starves
// the sibling's ds_read issue (m190: setprio hurts lockstep GEMM).
__global__ __launch_bounds__(512, 2) void gemm256_kernel(
        const __hip_bfloat16* __restrict__ X, const __hip_bfloat16* __restrict__ W,
        float* __restrict__ Z) {
    __shared__ short smem[65536];   // 128 KiB: [buf2][A 16K | B 16K elems]

    const int b = blockIdx.x;                 // 512 blocks, 512 % 8 == 0
    const int swz = (b & 7) * 64 + (b >> 3);  // XCD-bijective
    const int bm = swz >> 4, bn = swz & 15;   // 32 x 16 tiles

    const int tid = threadIdx.x;
    const int lane = tid & 63, wid = tid >> 6;
    const int wm = wid >> 2, wn = wid & 3;
    const int lr = lane & 15, lk = lane >> 4;
    const int swb = (lr & 7) << 4;                       // read-side XOR (bytes)
    const int c0 = (((lk << 4)) ^ swb) >> 1;             // kk=0 col (elements)
    const int c1 = ((64 | (lk << 4)) ^ swb) >> 1;        // kk=1 col (elements)
    const int wbase = wid << 9;

    const int grow = tid >> 3;
    const int scol = (((tid & 7) ^ (grow & 7)) << 3);    // pre-swizzled source col
    const __hip_bfloat16* gA = X + (size_t)(bm * 256 + grow) * NDIM + scol;
    const __hip_bfloat16* gB = W + (size_t)(bn * 256 + grow) * NDIM + scol;

#define STA2(OFS, H, Q, BUF) gld_lds16(gA + (size_t)(((H) * 128 + (Q) * 64) * NDIM) + (OFS), \
        &smem[(BUF) * 32768 + (H) * 8192 + (Q) * 4096 + wbase])
#define STB2(OFS, H, Q, BUF) gld_lds16(gB + (size_t)(((H) * 128 + (Q) * 64) * NDIM) + (OFS), \
        &smem[(BUF) * 32768 + 16384 + (H) * 8192 + (Q) * 4096 + wbase])
#define STAGE_A(OFS, BUF) do { STA2(OFS,0,0,BUF); STA2(OFS,0,1,BUF); \
                               STA2(OFS,1,0,BUF); STA2(OFS,1,1,BUF); } while (0)
#define STAGE_B(OFS, BUF) do { STB2(OFS,0,0,BUF); STB2(OFS,0,1,BUF); \
                               STB2(OFS,1,0,BUF); STB2(OFS,1,1,BUF); } while (0)

#define RDA(D0, D1, D2, D3, M0, AB) do { \
    D0 = *(const short8*)((AB) + ((M0) * 16 + lr) * 64 + c0); \
    D1 = *(const short8*)((AB) + ((M0) * 16 + lr) * 64 + c1); \
    D2 = *(const short8*)((AB) + ((M0) * 16 + 16 + lr) * 64 + c0); \
    D3 = *(const short8*)((AB) + ((M0) * 16 + 16 + lr) * 64 + c1); \
} while (0)

#define RDB(BARR, BUF) do { \
    const short* bB_ = smem + (BUF) * 32768 + 16384 + (wn * 64 + lr) * 64; \
    _Pragma("unroll") \
    for (int n = 0; n < 4; ++n) { \
        BARR[2 * n]     = *(const short8*)(bB_ + n * 1024 + c0); \
        BARR[2 * n + 1] = *(const short8*)(bB_ + n * 1024 + c1); \
    } \
} while (0)

#define MFMA2(A0, A1, E0, E1, M0, BF) do { \
    _Pragma("unroll") \
    for (int n = 0; n < 4; ++n) \
        acc[M0][n] = __builtin_amdgcn_mfma_f32_16x16x32_bf16(A0, BF[2 * n], acc[M0][n], 0, 0, 0); \
    _Pragma("unroll") \
    for (int n = 0; n < 4; ++n) \
        acc[(M0) + 1][n] = __builtin_amdgcn_mfma_f32_16x16x32_bf16(E0, BF[2 * n], acc[(M0) + 1][n], 0, 0, 0); \
    _Pragma("unroll") \
    for (int n = 0; n < 4; ++n) \
        acc[M0][n] = __builtin_amdgcn_mfma_f32_16x16x32_bf16(A1, BF[2 * n + 1], acc[M0][n], 0, 0, 0); \
    _Pragma("unroll") \
    for (int n = 0; n < 4; ++n) \
        acc[(M0) + 1][n] = __builtin_amdgcn_mfma_f32_16x16x32_bf16(E1, BF[2 * n + 1], acc[(M0) + 1][n], 0, 0, 0); \
} while (0)

#define TILE(CUR, BF, BN, DO_STA, DO_STB, DO_BN, LAST) do { \
    const short* aBase = smem + (CUR) * 32768 + wm * 8192; \
    if (DO_STA) STAGE_A(64, 1 - (CUR)); \
    if (DO_STB) STAGE_B(128, (CUR)); \
    RDA(xa0, xa1, xb0, xb1, 0, aBase); \
    RDA(ya0, ya1, yb0, yb1, 2, aBase); \
    MFMA2(xa0, xa1, xb0, xb1, 0, BF); \
    RDA(xa0, xa1, xb0, xb1, 4, aBase); \
    MFMA2(ya0, ya1, yb0, yb1, 2, BF); \
    RDA(ya0, ya1, yb0, yb1, 6, aBase); \
    if (DO_BN) RDB(BN, 1 - (CUR)); \
    MFMA2(xa0, xa1, xb0, xb1, 4, BF); \
    MFMA2(ya0, ya1, yb0, yb1, 6, BF); \
    if (!(LAST)) { \
        asm volatile("s_waitcnt lgkmcnt(0)" ::: "memory"); \
        asm volatile("s_waitcnt vmcnt(0)" ::: "memory"); \
        __builtin_amdgcn_s_barrier(); \
    } \
    gA += 64; gB += 64; \
} while (0)

    f32x4 acc[8][4];
#pragma unroll
    for (int m = 0; m < 8; ++m)
#pragma unroll
        for (int n = 0; n < 4; ++n) acc[m][n] = 0.f;

    short8 B0r[8], B1r[8];
    short8 xa0, xa1, xb0, xb1, ya0, ya1, yb0, yb1;

    // prologue: stage kt0 (A+B) + kt1.B; drain fully; prefetch Bf(0) to regs
    STAGE_A(0, 0);
    STAGE_B(0, 0);
    STAGE_B(64, 1);
    asm volatile("s_waitcnt vmcnt(0)" ::: "memory");   // kt0 + kt1.B resident
    __builtin_amdgcn_s_barrier();
    RDB(B0r, 0);
    asm volatile("s_waitcnt lgkmcnt(0)" ::: "memory"); // B(0) regs before STB(2)
    __builtin_amdgcn_s_barrier();

    for (int i = 0; i < 31; ++i) {              // kt = 0..61
        TILE(0, B0r, B1r, 1, 1, 1, 0);
        TILE(1, B1r, B0r, 1, 1, 1, 0);
    }
    TILE(0, B0r, B1r, 1, 0, 1, 0);              // kt = 62: no STB
    TILE(1, B1r, B0r, 0, 0, 0, 1);              // kt = 63: compute only

    // epilogue: C/D layout col=lane&15, row=(lane>>4)*4+reg
    const size_t r0 = (size_t)bm * 256 + wm * 128 + (lk << 2);
    const size_t cb0 = (size_t)bn * 256 + wn * 64 + lr;
#pragma unroll
    for (int m = 0; m < 8; ++m)
#pragma unroll
        for (int n = 0; n < 4; ++n) {
            const size_t col = cb0 + n * 16;
#pragma unroll
            for (int j = 0; j < 4; ++j)
                Z[(r0 + m * 16 + j) * MDIM + col] = acc[m][n][j];
        }
}

// ---------------------------------------------------------------------------
extern "C" void kernel_launch(void* const* d_in, const int* in_sizes, int n_in,
                              void* d_out, int out_size, void* d_ws, size_t ws_size,
                              hipStream_t stream) {
    const float* input  = (const float*)d_in[0];
    const int*   Qidxs  = (const int*)d_in[1];
    const float* cbvals = (const float*)d_in[2];
    const float* SU     = (const float*)d_in[3];
    const float* SV     = (const float*)d_in[4];
    const float* Wscale = (const float*)d_in[5];
    const float* A      = (const float*)d_in[6];
    const float* B      = (const float*)d_in[7];
    float* out = (float*)d_out;

    __hip_bfloat16* xbf = (__hip_bfloat16*)d_ws;
    __hip_bfloat16* wbf = (__hip_bfloat16*)((char*)d_ws + (size_t)T_ROWS * NDIM * 2);

    fwht_in_kernel<<<T_ROWS, 256, 0, stream>>>(input, SU, xbf);
    dequant_kernel<<<dim3(MDIM / 64, MDIM / 64), 256, 0, stream>>>(
        Qidxs, cbvals, Wscale, A, B, wbf);
    gemm256_kernel<<<(T_ROWS / 256) * (MDIM / 256), 512, 0, stream>>>(xbf, wbf, out);
    fwht_out_kernel<<<T_ROWS, 256, 0, stream>>>(out, SV);
}

// Round 6
// 351.113 us; speedup vs baseline: 1.5932x; 1.0164x over previous
//
#include <hip/hip_runtime.h>
#include <hip/hip_bf16.h>

// QuantizedLinear: T=8192 rows, N=K=4096, M=4096, RANK=64, CODESZ=8, CB=256.
// ws layout: x_bf16 [8192*4096] + W_eff bf16 [4096*4096] = 96 MiB.

typedef __attribute__((ext_vector_type(8))) short short8;
typedef __attribute__((ext_vector_type(4))) float f32x4;

#define T_ROWS 8192
#define NDIM   4096
#define MDIM   4096
#define NT     (NDIM / 64)   // 64 K-tiles of BK=64

// ---------------------------------------------------------------------------
// global -> LDS async copy, 16B/lane. LDS dest: wave-uniform base + lane*16.
__device__ __forceinline__ void gld_lds16(const void* g, void* lds_uniform) {
    __builtin_amdgcn_global_load_lds(
        (const __attribute__((address_space(1))) unsigned int*)(unsigned long long)(uintptr_t)g,
        (__attribute__((address_space(3))) unsigned int*)(unsigned int)(uintptr_t)lds_uniform,
        16, 0, 0);
}

__device__ __forceinline__ void bfly(float& a, float& b) {
    float s = a + b, d = a - b; a = s; b = d;
}

// ---------------------------------------------------------------------------
// 3-phase in-register FWHT-4096 (16 elems/thread, 2 syncthreads).
__device__ __forceinline__ void fwht16(float* v) {
#pragma unroll
    for (int h = 1; h <= 8; h <<= 1)
#pragma unroll
        for (int j = 0; j < 16; ++j)
            if (!(j & h)) bfly(v[j], v[j | h]);
}

// k1: x = fwht(input * SU) / 64, bf16 out.
__global__ __launch_bounds__(256) void fwht_in_kernel(
        const float* __restrict__ in, const float* __restrict__ SU,
        __hip_bfloat16* __restrict__ xout) {
    __shared__ float sh[4352];
    const int t = threadIdx.x;
    const size_t r = blockIdx.x;
    float v[16];
    {
        const float4* s4 = (const float4*)(in + (r << 12) + t * 16);
        const float4* u4 = (const float4*)(SU + t * 16);
#pragma unroll
        for (int q = 0; q < 4; ++q) {
            float4 a = s4[q], u = u4[q];
            v[4 * q + 0] = a.x * u.x; v[4 * q + 1] = a.y * u.y;
            v[4 * q + 2] = a.z * u.z; v[4 * q + 3] = a.w * u.w;
        }
    }
    fwht16(v);                                   // bits 0-3
#pragma unroll
    for (int j = 0; j < 16; ++j) sh[17 * t + j] = v[j];
    __syncthreads();
    const int baseB = (t & 15) + 272 * (t >> 4);
#pragma unroll
    for (int j = 0; j < 16; ++j) v[j] = sh[baseB + 17 * j];
    fwht16(v);                                   // bits 4-7
#pragma unroll
    for (int j = 0; j < 16; ++j) sh[baseB + 17 * j] = v[j];
    __syncthreads();
    const int baseC = t + (t >> 4);
#pragma unroll
    for (int j = 0; j < 16; ++j) v[j] = sh[baseC + 272 * j];
    fwht16(v);                                   // bits 8-11
    __hip_bfloat16* dst = xout + (r << 12);
#pragma unroll
    for (int j = 0; j < 16; ++j)
        dst[(j << 8) + t] = __float2bfloat16(v[j] * 0.015625f);
}

// k4: z = fwht(z) / 64 * SV, in place (f32).
__global__ __launch_bounds__(256) void fwht_out_kernel(
        float* __restrict__ z, const float* __restrict__ SV) {
    __shared__ float sh[4352];
    const int t = threadIdx.x;
    const size_t r = blockIdx.x;
    float* row = z + (r << 12);
    float v[16];
    {
        const float4* s4 = (const float4*)(row + t * 16);
#pragma unroll
        for (int q = 0; q < 4; ++q) {
            float4 a = s4[q];
            v[4 * q + 0] = a.x; v[4 * q + 1] = a.y;
            v[4 * q + 2] = a.z; v[4 * q + 3] = a.w;
        }
    }
    fwht16(v);
#pragma unroll
    for (int j = 0; j < 16; ++j) sh[17 * t + j] = v[j];
    __syncthreads();
    const int baseB = (t & 15) + 272 * (t >> 4);
#pragma unroll
    for (int j = 0; j < 16; ++j) v[j] = sh[baseB + 17 * j];
    fwht16(v);
#pragma unroll
    for (int j = 0; j < 16; ++j) sh[baseB + 17 * j] = v[j];
    __syncthreads();
    const int baseC = t + (t >> 4);
#pragma unroll
    for (int j = 0; j < 16; ++j) v[j] = sh[baseC + 272 * j];
    fwht16(v);
#pragma unroll
    for (int j = 0; j < 16; ++j)
        row[(j << 8) + t] = v[j] * 0.015625f * SV[(j << 8) + t];
}

// ---------------------------------------------------------------------------
// k2: W_eff = dequant + A@B, bf16. (unchanged)
__global__ __launch_bounds__(256) void dequant_kernel(
        const int* __restrict__ Qidxs, const float* __restrict__ cb,
        const float* __restrict__ Wscale, const float* __restrict__ A,
        const float* __restrict__ B, __hip_bfloat16* __restrict__ Weff) {
    __shared__ float At[64][68];
    __shared__ float Bs[64][68];
    __shared__ float cbs[2048];
    const int t = threadIdx.x;
    const int i0 = blockIdx.y * 64, j0 = blockIdx.x * 64;

    {
        const float* ga = A + (size_t)i0 * 64;
        const int r = t >> 2, kb = (t & 3) * 16;
#pragma unroll
        for (int j = 0; j < 16; ++j) At[kb + j][r] = ga[t * 16 + j];
        const int k = t >> 2, c0 = (t & 3) * 16;
        const float* gb = B + (size_t)k * NDIM + j0 + c0;
#pragma unroll
        for (int j = 0; j < 16; ++j) Bs[k][c0 + j] = gb[j];
#pragma unroll
        for (int j = 0; j < 8; ++j) cbs[t * 8 + j] = cb[t * 8 + j];
    }
    __syncthreads();

    const int ty = t >> 4, tx = t & 15;
    float acc[4][4];
#pragma unroll
    for (int a = 0; a < 4; ++a)
#pragma unroll
        for (int b = 0; b < 4; ++b) acc[a][b] = 0.f;

#pragma unroll 8
    for (int k = 0; k < 64; ++k) {
        const float4 av = *(const float4*)&At[k][ty * 4];
        const float4 bv = *(const float4*)&Bs[k][tx * 4];
        const float aa[4] = {av.x, av.y, av.z, av.w};
        const float bb[4] = {bv.x, bv.y, bv.z, bv.w};
#pragma unroll
        for (int ii = 0; ii < 4; ++ii)
#pragma unroll
            for (int jj = 0; jj < 4; ++jj) acc[ii][jj] += aa[ii] * bb[jj];
    }

    const float wsc = Wscale[0];
#pragma unroll
    for (int ii = 0; ii < 4; ++ii) {
        const int i = i0 + ty * 4 + ii;
        const int* qrow = Qidxs + (size_t)i * (NDIM / 8);
        union { __hip_bfloat16 h[4]; unsigned long long u; } pk;
#pragma unroll
        for (int jj = 0; jj < 4; ++jj) {
            const int j = j0 + tx * 4 + jj;
            const int idx = qrow[j >> 3];
            const float val = cbs[idx * 8 + (j & 7)] * wsc + acc[ii][jj];
            pk.h[jj] = __float2bfloat16(val);
        }
        *(unsigned long long*)&Weff[(size_t)i * NDIM + j0 + tx * 4] = pk.u;
    }
}

// ---------------------------------------------------------------------------
// k3: 256x256x(BK=64) bf16 NT GEMM — ROTATED single-barrier schedule.
// Tile kt's last MFMA cluster (m6) executes AFTER the end-of-kt barrier, and
// the next tile's A.m0 fragments are LDS-prefetched right after the barrier,
// so the matrix pipe never drains at tile boundaries:
//   [entry, post-barrier of kt-1]:  regs hold Bf(kt) [RDB'd mid kt-1],
//       A.m0(kt) [PFA'd post-barrier], ya=A.m6(kt-1)
//   MFMA m6(kt-1)            <- covers the post-barrier read burst
//   STA(kt+1)->!CUR ; STB(kt+2)->CUR
//   RDA m2; MFMA m0 | RDA m4; MFMA m2 | RDB Bf(kt+1)<-!CUR.B ; RDA m6; MFMA m4
//   lgkmcnt(4)  <- RDB drained (WAR vs next tile's STB); RDA m6 floats across
//   vmcnt(0)    <- all stores >=1 tile old: free; publishes !CUR block-wide
//   s_barrier ; PFA: RDA m0(kt+1) <- !CUR.A
// Soundness: RDB reads B(kt+1) staged at kt-1, resident since kt's entry
// barrier (vmcnt(0) before every barrier). PFA reads A(kt+1) staged at kt,
// published by this barrier. No mid-tile barriers, no setprio.
__global__ __launch_bounds__(512, 2) void gemm256_kernel(
        const __hip_bfloat16* __restrict__ X, const __hip_bfloat16* __restrict__ W,
        float* __restrict__ Z) {
    __shared__ short smem[65536];   // 128 KiB: [buf2][A 16K | B 16K elems]

    const int b = blockIdx.x;                 // 512 blocks, 512 % 8 == 0
    const int swz = (b & 7) * 64 + (b >> 3);  // XCD-bijective
    const int bm = swz >> 4, bn = swz & 15;   // 32 x 16 tiles

    const int tid = threadIdx.x;
    const int lane = tid & 63, wid = tid >> 6;
    const int wm = wid >> 2, wn = wid & 3;
    const int lr = lane & 15, lk = lane >> 4;
    const int swb = (lr & 7) << 4;                       // read-side XOR (bytes)
    const int c0 = (((lk << 4)) ^ swb) >> 1;             // kk=0 col (elements)
    const int c1 = ((64 | (lk << 4)) ^ swb) >> 1;        // kk=1 col (elements)
    const int wbase = wid << 9;

    const int grow = tid >> 3;
    const int scol = (((tid & 7) ^ (grow & 7)) << 3);    // pre-swizzled source col
    const __hip_bfloat16* gA = X + (size_t)(bm * 256 + grow) * NDIM + scol;
    const __hip_bfloat16* gB = W + (size_t)(bn * 256 + grow) * NDIM + scol;

#define STA2(OFS, H, Q, BUF) gld_lds16(gA + (size_t)(((H) * 128 + (Q) * 64) * NDIM) + (OFS), \
        &smem[(BUF) * 32768 + (H) * 8192 + (Q) * 4096 + wbase])
#define STB2(OFS, H, Q, BUF) gld_lds16(gB + (size_t)(((H) * 128 + (Q) * 64) * NDIM) + (OFS), \
        &smem[(BUF) * 32768 + 16384 + (H) * 8192 + (Q) * 4096 + wbase])
#define STAGE_A(OFS, BUF) do { STA2(OFS,0,0,BUF); STA2(OFS,0,1,BUF); \
                               STA2(OFS,1,0,BUF); STA2(OFS,1,1,BUF); } while (0)
#define STAGE_B(OFS, BUF) do { STB2(OFS,0,0,BUF); STB2(OFS,0,1,BUF); \
                               STB2(OFS,1,0,BUF); STB2(OFS,1,1,BUF); } while (0)

#define RDA(D0, D1, D2, D3, M0, AB) do { \
    D0 = *(const short8*)((AB) + ((M0) * 16 + lr) * 64 + c0); \
    D1 = *(const short8*)((AB) + ((M0) * 16 + lr) * 64 + c1); \
    D2 = *(const short8*)((AB) + ((M0) * 16 + 16 + lr) * 64 + c0); \
    D3 = *(const short8*)((AB) + ((M0) * 16 + 16 + lr) * 64 + c1); \
} while (0)

#define RDB(BARR, BUF) do { \
    const short* bB_ = smem + (BUF) * 32768 + 16384 + (wn * 64 + lr) * 64; \
    _Pragma("unroll") \
    for (int n = 0; n < 4; ++n) { \
        BARR[2 * n]     = *(const short8*)(bB_ + n * 1024 + c0); \
        BARR[2 * n + 1] = *(const short8*)(bB_ + n * 1024 + c1); \
    } \
} while (0)

#define MFMA2(A0, A1, E0, E1, M0, BF) do { \
    _Pragma("unroll") \
    for (int n = 0; n < 4; ++n) \
        acc[M0][n] = __builtin_amdgcn_mfma_f32_16x16x32_bf16(A0, BF[2 * n], acc[M0][n], 0, 0, 0); \
    _Pragma("unroll") \
    for (int n = 0; n < 4; ++n) \
        acc[(M0) + 1][n] = __builtin_amdgcn_mfma_f32_16x16x32_bf16(E0, BF[2 * n], acc[(M0) + 1][n], 0, 0, 0); \
    _Pragma("unroll") \
    for (int n = 0; n < 4; ++n) \
        acc[M0][n] = __builtin_amdgcn_mfma_f32_16x16x32_bf16(A1, BF[2 * n + 1], acc[M0][n], 0, 0, 0); \
    _Pragma("unroll") \
    for (int n = 0; n < 4; ++n) \
        acc[(M0) + 1][n] = __builtin_amdgcn_mfma_f32_16x16x32_bf16(E1, BF[2 * n + 1], acc[(M0) + 1][n], 0, 0, 0); \
} while (0)

// Rotated tile body. M6P: run prev tile's m6 at entry (operands ya + BN).
#define TILE_ROT(CUR, BF, BN, M6P, DO_STA, DO_STB, DO_RDB, DO_PFA, DO_ENDBAR) do { \
    const short* aBase = smem + (CUR) * 32768 + wm * 8192; \
    if (M6P) MFMA2(ya0, ya1, yb0, yb1, 6, BN); \
    if (DO_STA) STAGE_A(64, 1 - (CUR)); \
    if (DO_STB) STAGE_B(128, (CUR)); \
    RDA(ya0, ya1, yb0, yb1, 2, aBase); \
    MFMA2(xa0, xa1, xb0, xb1, 0, BF); \
    RDA(xa0, xa1, xb0, xb1, 4, aBase); \
    MFMA2(ya0, ya1, yb0, yb1, 2, BF); \
    if (DO_RDB) RDB(BN, 1 - (CUR)); \
    RDA(ya0, ya1, yb0, yb1, 6, aBase); \
    MFMA2(xa0, xa1, xb0, xb1, 4, BF); \
    if (DO_ENDBAR) { \
        asm volatile("s_waitcnt lgkmcnt(4)" ::: "memory"); \
        asm volatile("s_waitcnt vmcnt(0)" ::: "memory"); \
        __builtin_amdgcn_s_barrier(); \
    } \
    if (DO_PFA) RDA(xa0, xa1, xb0, xb1, 0, smem + (1 - (CUR)) * 32768 + wm * 8192); \
    gA += 64; gB += 64; \
} while (0)

    f32x4 acc[8][4];
#pragma unroll
    for (int m = 0; m < 8; ++m)
#pragma unroll
        for (int n = 0; n < 4; ++n) acc[m][n] = 0.f;

    short8 B0r[8], B1r[8];
    short8 xa0, xa1, xb0, xb1, ya0, ya1, yb0, yb1;

    // prologue: stage kt0 (A+B) + kt1.B; drain; prefetch Bf(0) + A.m0(0)
    STAGE_A(0, 0);
    STAGE_B(0, 0);
    STAGE_B(64, 1);
    asm volatile("s_waitcnt vmcnt(0)" ::: "memory");   // kt0 + kt1.B resident
    __builtin_amdgcn_s_barrier();
    RDB(B0r, 0);
    RDA(xa0, xa1, xb0, xb1, 0, smem + wm * 8192);
    asm volatile("s_waitcnt lgkmcnt(0)" ::: "memory"); // regs loaded before STB(2)
    __builtin_amdgcn_s_barrier();

    // kt = 0 (no prev m6)
    TILE_ROT(0, B0r, B1r, 0, 1, 1, 1, 1, 1);
    for (int i = 0; i < 30; ++i) {              // kt = 1..60
        TILE_ROT(1, B1r, B0r, 1, 1, 1, 1, 1, 1);
        TILE_ROT(0, B0r, B1r, 1, 1, 1, 1, 1, 1);
    }
    TILE_ROT(1, B1r, B0r, 1, 1, 1, 1, 1, 1);    // kt = 61
    TILE_ROT(0, B0r, B1r, 1, 1, 0, 1, 1, 1);    // kt = 62: no STB(64)
    TILE_ROT(1, B1r, B0r, 1, 0, 0, 0, 0, 0);    // kt = 63: compute only
    MFMA2(ya0, ya1, yb0, yb1, 6, B1r);          // m6 of kt = 63

    // epilogue: C/D layout col=lane&15, row=(lane>>4)*4+reg
    const size_t r0 = (size_t)bm * 256 + wm * 128 + (lk << 2);
    const size_t cb0 = (size_t)bn * 256 + wn * 64 + lr;
#pragma unroll
    for (int m = 0; m < 8; ++m)
#pragma unroll
        for (int n = 0; n < 4; ++n) {
            const size_t col = cb0 + n * 16;
#pragma unroll
            for (int j = 0; j < 4; ++j)
                Z[(r0 + m * 16 + j) * MDIM + col] = acc[m][n][j];
        }
}

// ---------------------------------------------------------------------------
extern "C" void kernel_launch(void* const* d_in, const int* in_sizes, int n_in,
                              void* d_out, int out_size, void* d_ws, size_t ws_size,
                              hipStream_t stream) {
    const float* input  = (const float*)d_in[0];
    const int*   Qidxs  = (const int*)d_in[1];
    const float* cbvals = (const float*)d_in[2];
    const float* SU     = (const float*)d_in[3];
    const float* SV     = (const float*)d_in[4];
    const float* Wscale = (const float*)d_in[5];
    const float* A      = (const float*)d_in[6];
    const float* B      = (const float*)d_in[7];
    float* out = (float*)d_out;

    __hip_bfloat16* xbf = (__hip_bfloat16*)d_ws;
    __hip_bfloat16* wbf = (__hip_bfloat16*)((char*)d_ws + (size_t)T_ROWS * NDIM * 2);

    fwht_in_kernel<<<T_ROWS, 256, 0, stream>>>(input, SU, xbf);
    dequant_kernel<<<dim3(MDIM / 64, MDIM / 64), 256, 0, stream>>>(
        Qidxs, cbvals, Wscale, A, B, wbf);
    gemm256_kernel<<<(T_ROWS / 256) * (MDIM / 256), 512, 0, stream>>>(xbf, wbf, out);
    fwht_out_kernel<<<T_ROWS, 256, 0, stream>>>(out, SV);
}